// Round 1
// baseline (2505.757 us; speedup 1.0000x reference)
//
#include <hip/hip_runtime.h>
#include <math.h>

#define Bt 16
#define St 512
#define Dt 768
#define Ht 12
#define DKt 64

// ---------------- LayerNorm: one block (256 thr) per row of 768 ----------------
__global__ __launch_bounds__(256)
void ln_kernel(const float* __restrict__ x, const float* __restrict__ g,
               const float* __restrict__ be, float* __restrict__ out)
{
    int row = blockIdx.x;
    const float* xr = x + (size_t)row * Dt;
    float* orow = out + (size_t)row * Dt;
    int t = threadIdx.x;
    float v0 = xr[t], v1 = xr[t + 256], v2 = xr[t + 512];
    float s = v0 + v1 + v2;
    #pragma unroll
    for (int off = 32; off; off >>= 1) s += __shfl_xor(s, off, 64);
    __shared__ float r1[4], r2[4];
    if ((t & 63) == 0) r1[t >> 6] = s;
    __syncthreads();
    float mu = (r1[0] + r1[1] + r1[2] + r1[3]) * (1.0f / Dt);
    float d0 = v0 - mu, d1 = v1 - mu, d2 = v2 - mu;
    float sq = d0 * d0 + d1 * d1 + d2 * d2;
    #pragma unroll
    for (int off = 32; off; off >>= 1) sq += __shfl_xor(sq, off, 64);
    if ((t & 63) == 0) r2[t >> 6] = sq;
    __syncthreads();
    float var = (r2[0] + r2[1] + r2[2] + r2[3]) * (1.0f / Dt);
    float rs = 1.0f / sqrtf(var + 1e-12f);
    orow[t]       = d0 * rs * g[t]       + be[t];
    orow[t + 256] = d1 * rs * g[t + 256] + be[t + 256];
    orow[t + 512] = d2 * rs * g[t + 512] + be[t + 512];
}

// ---------------- f32 GEMM: C[8192,768-tile] = A[8192,768] @ W[768(ldw slice),768] ----
// tile 128x64, 256 threads, 8x4 micro-tile. K fixed = 768. lda = ldc = 768.
// EPI: 0 = +bias, 1 = gelu(+bias), 2 = +bias+residual, 3 = accumulate into C
#define BMg 128
#define BNg 64
#define BKg 16

__device__ __forceinline__ float gelu_exact(float v) {
    return 0.5f * v * (1.0f + erff(v * 0.70710678118654752f));
}

template<int EPI>
__global__ __launch_bounds__(256)
void gemm_kernel(const float* __restrict__ A, const float* __restrict__ W,
                 const float* __restrict__ bias, const float* __restrict__ res,
                 float* __restrict__ C, int ldw)
{
    __shared__ float As[BKg][BMg + 4];   // transposed: As[k][m]
    __shared__ float Ws[BKg][BNg + 4];
    int t = threadIdx.x;
    int bn = blockIdx.x * BNg;
    int bm = blockIdx.y * BMg;
    int tr = t & 15;
    int tc = t >> 4;
    float acc[8][4] = {};
    for (int k0 = 0; k0 < Dt; k0 += BKg) {
        #pragma unroll
        for (int i = 0; i < 2; ++i) {
            int idx = t + i * 256;
            int r = idx >> 2;
            int c4 = (idx & 3) << 2;
            float4 av = *(const float4*)(A + (size_t)(bm + r) * Dt + k0 + c4);
            As[c4 + 0][r] = av.x; As[c4 + 1][r] = av.y;
            As[c4 + 2][r] = av.z; As[c4 + 3][r] = av.w;
        }
        {
            int r = t >> 4;
            int c4 = (t & 15) << 2;
            *(float4*)(&Ws[r][c4]) = *(const float4*)(W + (size_t)(k0 + r) * ldw + bn + c4);
        }
        __syncthreads();
        #pragma unroll
        for (int kk = 0; kk < BKg; ++kk) {
            float4 A0 = *(const float4*)(&As[kk][tr * 4]);
            float4 A1 = *(const float4*)(&As[kk][tr * 4 + 64]);
            float4 Wv = *(const float4*)(&Ws[kk][tc * 4]);
            float a[8] = {A0.x, A0.y, A0.z, A0.w, A1.x, A1.y, A1.z, A1.w};
            float w[4] = {Wv.x, Wv.y, Wv.z, Wv.w};
            #pragma unroll
            for (int i2 = 0; i2 < 8; ++i2)
                #pragma unroll
                for (int j2 = 0; j2 < 4; ++j2)
                    acc[i2][j2] += a[i2] * w[j2];
        }
        __syncthreads();
    }
    float4 bv = make_float4(0.f, 0.f, 0.f, 0.f);
    if (EPI != 3) bv = *(const float4*)(bias + bn + tc * 4);
    #pragma unroll
    for (int i = 0; i < 8; ++i) {
        int m = bm + ((i >> 2) << 6) + tr * 4 + (i & 3);
        float* cp = C + (size_t)m * Dt + bn + tc * 4;
        float4 o = make_float4(acc[i][0], acc[i][1], acc[i][2], acc[i][3]);
        if (EPI != 3) { o.x += bv.x; o.y += bv.y; o.z += bv.z; o.w += bv.w; }
        if (EPI == 1) { o.x = gelu_exact(o.x); o.y = gelu_exact(o.y);
                        o.z = gelu_exact(o.z); o.w = gelu_exact(o.w); }
        if (EPI == 2) {
            float4 rv = *(const float4*)(res + (size_t)m * Dt + bn + tc * 4);
            o.x += rv.x; o.y += rv.y; o.z += rv.z; o.w += rv.w;
        }
        if (EPI == 3) {
            float4 pv = *(const float4*)cp;
            o.x += pv.x; o.y += pv.y; o.z += pv.z; o.w += pv.w;
        }
        *(float4*)cp = o;
    }
}

// ---------------- group attention: neighbor dots + 2-entry softmax ----------------
__global__ __launch_bounds__(256)
void group_scores_kernel(const float* __restrict__ qg, const float* __restrict__ kg,
                         const int* __restrict__ am,
                         float* __restrict__ smU, float* __restrict__ smD,
                         int* __restrict__ emptyF)
{
    int gi = blockIdx.x;
    int b = gi >> 9, s = gi & 511;
    int t = threadIdx.x;
    const float* qr = qg + (size_t)gi * Dt;
    bool hasU = (s < 511) && (am[(b << 9) + s + 1] != 0);
    bool hasD = (s > 0)   && (am[(b << 9) + s - 1] != 0);
    float su = 0.0f, sd = 0.0f;
    if (hasU) {
        const float* kr = kg + (size_t)(gi + 1) * Dt;
        for (int c = t; c < Dt; c += 256) su += qr[c] * kr[c];
    }
    if (hasD) {
        const float* kr = kg + (size_t)(gi - 1) * Dt;
        for (int c = t; c < Dt; c += 256) sd += qr[c] * kr[c];
    }
    #pragma unroll
    for (int off = 32; off; off >>= 1) { su += __shfl_xor(su, off, 64); sd += __shfl_xor(sd, off, 64); }
    __shared__ float rU[4], rD[4];
    if ((t & 63) == 0) { rU[t >> 6] = su; rD[t >> 6] = sd; }
    __syncthreads();
    if (t == 0) {
        su = (rU[0] + rU[1] + rU[2] + rU[3]) * (1.0f / Dt);   // scores / D
        sd = (rD[0] + rD[1] + rD[2] + rD[3]) * (1.0f / Dt);
        float u, d2; int emp = 0;
        if (hasU && hasD) {
            float m = fmaxf(su, sd);
            float eu = __expf(su - m), ed = __expf(sd - m);
            float inv = 1.0f / (eu + ed);
            u = eu * inv; d2 = ed * inv;
        } else if (hasU) { u = 1.0f; d2 = 0.0f; }
        else if (hasD)   { u = 0.0f; d2 = 1.0f; }
        else { u = d2 = 1.0f / 512.0f; emp = 1; }   // all-masked row: softmax uniform
        smU[gi] = u; smD[gi] = d2; emptyF[gi] = emp;
    }
}

// neigh[b,i,j] = prior + (1-prior)*sqrt(f(i,j)*f(j,i) + 1e-9)
__global__ __launch_bounds__(512)
void neigh_kernel(const float* __restrict__ prior,
                  const float* __restrict__ smU, const float* __restrict__ smD,
                  const int* __restrict__ emptyF, float* __restrict__ ne_out)
{
    int bi = blockIdx.x;           // b*512 + i
    int j  = threadIdx.x;
    int b = bi >> 9, i = bi & 511;
    int bj = (b << 9) + j;
    const float invS = 1.0f / 512.0f;
    float fij, fji;
    if (j == i + 1)      { fij = smU[bi]; fji = smD[bj]; }
    else if (j == i - 1) { fij = smD[bi]; fji = smU[bj]; }
    else { fij = emptyF[bi] ? invS : 0.0f; fji = emptyF[bj] ? invS : 0.0f; }
    float val = sqrtf(fij * fji + 1e-9f);
    float pr = prior[(size_t)bi * 512 + j];
    ne_out[(size_t)bi * 512 + j] = pr + (1.0f - pr) * val;
}

// per-batch prefix sums of l_j = log(neigh[j][j+1]+1e-9); one wave per batch
__global__ __launch_bounds__(64)
void prefix_kernel(const float* __restrict__ ne, float* __restrict__ P)
{
    int b = blockIdx.x;
    int l = threadIdx.x;
    float lv[8];
    float run = 0.0f;
    #pragma unroll
    for (int e = 0; e < 8; ++e) {
        int j = l * 8 + e;
        float lj = 0.0f;
        if (j < 511) lj = logf(ne[((size_t)(b * 512 + j)) * 512 + (j + 1)] + 1e-9f);
        lv[e] = run;
        run += lj;
    }
    float tot = run;
    float scan = tot;
    #pragma unroll
    for (int off = 1; off < 64; off <<= 1) {
        float n = __shfl_up(scan, off, 64);
        if (l >= off) scan += n;
    }
    float excl = scan - tot;
    #pragma unroll
    for (int e = 0; e < 8; ++e)
        P[b * 512 + l * 8 + e] = excl + lv[e];
}

// C[b,i,j]: j>i -> exp(P[j]-P[i])+1e-9 ; j<i symmetric ; diag -> neigh[i][i]
__global__ __launch_bounds__(512)
void cfill_kernel(const float* __restrict__ P, const float* __restrict__ ne,
                  float* __restrict__ C_out)
{
    int bi = blockIdx.x;
    int j = threadIdx.x;
    int b = bi >> 9, i = bi & 511;
    float pi = P[bi], pj = P[(b << 9) + j];
    float v;
    if (j > i)      v = expf(pj - pi) + 1e-9f;
    else if (j < i) v = expf(pi - pj) + 1e-9f;
    else            v = ne[(size_t)bi * 512 + i];
    C_out[(size_t)bi * 512 + j] = v;
}

// ---------------- fused MHA core: per (b,h,16-row q-tile) --------------------------
#define QT 16
__global__ __launch_bounds__(256)
void mha_kernel(const float* __restrict__ q, const float* __restrict__ k,
                const float* __restrict__ v, const int* __restrict__ am,
                const float* __restrict__ Cmat, float* __restrict__ ctx)
{
    __shared__ float Qs[QT][68];
    __shared__ float KVs[64][68];     // K^T in phase A, V in phase B
    __shared__ float Sl[QT][516];
    int t = threadIdx.x;
    int blk = blockIdx.x;
    int qt = blk & 31;
    int h  = (blk >> 5) % Ht;
    int b  = blk / (32 * Ht);
    int hoff = h * DKt;
    int row0 = (b << 9) + qt * QT;
    int s0 = qt * QT;

    {   // stage Q tile [16][64]
        int r = t >> 4;
        int c4 = (t & 15) << 2;
        *(float4*)(&Qs[r][c4]) = *(const float4*)(q + (size_t)(row0 + r) * Dt + hoff + c4);
    }
    // ---- phase A: scores = Q K^T / 8 ----
    int rA = t & 15;
    int jg = t >> 4;
    for (int kb = 0; kb < 8; ++kb) {
        __syncthreads();
        {   // stage K^T: KVs[d][j]
            int j = t >> 2;
            int dq = t & 3;
            const float* kp = k + (size_t)((b << 9) + kb * 64 + j) * Dt + hoff;
            #pragma unroll
            for (int c = 0; c < 4; ++c) {
                int d0 = (dq + 4 * c) * 4;
                float4 kv = *(const float4*)(kp + d0);
                KVs[d0 + 0][j] = kv.x; KVs[d0 + 1][j] = kv.y;
                KVs[d0 + 2][j] = kv.z; KVs[d0 + 3][j] = kv.w;
            }
        }
        __syncthreads();
        float a0 = 0.f, a1 = 0.f, a2 = 0.f, a3 = 0.f;
        #pragma unroll 8
        for (int d = 0; d < 64; ++d) {
            float qv = Qs[rA][d];
            float4 kv = *(const float4*)(&KVs[d][jg * 4]);
            a0 += qv * kv.x; a1 += qv * kv.y; a2 += qv * kv.z; a3 += qv * kv.w;
        }
        float4 sc = make_float4(a0 * 0.125f, a1 * 0.125f, a2 * 0.125f, a3 * 0.125f);
        *(float4*)(&Sl[rA][kb * 64 + jg * 4]) = sc;
    }
    __syncthreads();
    // ---- masked softmax, then scale by C (p = softmax * C) ----
    {
        int w = t >> 6, l = t & 63;
        for (int rr = 0; rr < 4; ++rr) {
            int r = w * 4 + rr;
            int s = s0 + r;
            float m = -3.0e38f;
            for (int c = l; c < 512; c += 64) {
                bool ok = (am[(b << 9) + c] != 0) || (c == s);
                float sv = ok ? Sl[r][c] : -3.0e38f;
                m = fmaxf(m, sv);
            }
            #pragma unroll
            for (int off = 32; off; off >>= 1) m = fmaxf(m, __shfl_xor(m, off, 64));
            float sum = 0.0f;
            for (int c = l; c < 512; c += 64) {
                bool ok = (am[(b << 9) + c] != 0) || (c == s);
                float e = ok ? __expf(Sl[r][c] - m) : 0.0f;
                Sl[r][c] = e;
                sum += e;
            }
            #pragma unroll
            for (int off = 32; off; off >>= 1) sum += __shfl_xor(sum, off, 64);
            float inv = 1.0f / sum;
            const float* crow = Cmat + (size_t)((b << 9) + s) * 512;
            for (int c = l; c < 512; c += 64)
                Sl[r][c] *= inv * crow[c];
        }
    }
    // ---- phase B: ctx = P V ----
    int rB = t & 15;
    int dg = t >> 4;
    float o0 = 0.f, o1 = 0.f, o2 = 0.f, o3 = 0.f;
    for (int kb = 0; kb < 8; ++kb) {
        __syncthreads();
        {   // stage V: KVs[j][d]
            int j = t >> 2;
            int dq = t & 3;
            const float* vp = v + (size_t)((b << 9) + kb * 64 + j) * Dt + hoff;
            #pragma unroll
            for (int c = 0; c < 4; ++c) {
                int d0 = (dq + 4 * c) * 4;
                *(float4*)(&KVs[j][d0]) = *(const float4*)(vp + d0);
            }
        }
        __syncthreads();
        #pragma unroll 8
        for (int j = 0; j < 64; ++j) {
            float p = Sl[rB][kb * 64 + j];
            float4 vv = *(const float4*)(&KVs[j][dg * 4]);
            o0 += p * vv.x; o1 += p * vv.y; o2 += p * vv.z; o3 += p * vv.w;
        }
    }
    *(float4*)(ctx + (size_t)(row0 + rB) * Dt + hoff + dg * 4) =
        make_float4(o0, o1, o2, o3);
}

// -----------------------------------------------------------------------------------
extern "C" void kernel_launch(void* const* d_in, const int* in_sizes, int n_in,
                              void* d_out, int out_size, void* d_ws, size_t ws_size,
                              hipStream_t stream)
{
    (void)in_sizes; (void)n_in; (void)out_size; (void)ws_size;
    const float* x     = (const float*)d_in[0];
    const float* prior = (const float*)d_in[1];
    const int*   am    = (const int*)  d_in[2];
    const float* Wq = (const float*)d_in[3];   const float* bq = (const float*)d_in[4];
    const float* Wk = (const float*)d_in[5];   const float* bk = (const float*)d_in[6];
    const float* Wv = (const float*)d_in[7];   const float* bv = (const float*)d_in[8];
    const float* Wo = (const float*)d_in[9];   const float* bo = (const float*)d_in[10];
    const float* gWk = (const float*)d_in[11]; const float* gbk = (const float*)d_in[12];
    const float* gWq = (const float*)d_in[13]; const float* gbq = (const float*)d_in[14];
    const float* glng = (const float*)d_in[15]; const float* glnb = (const float*)d_in[16];
    const float* Wi = (const float*)d_in[17];  const float* bi = (const float*)d_in[18];
    const float* Wout = (const float*)d_in[19]; const float* bout = (const float*)d_in[20];
    const float* lng = (const float*)d_in[21]; const float* lnb = (const float*)d_in[22];

    float* out = (float*)d_out;
    float* o_layer = out;                         // [8192,768]  (also ctx / y scratch)
    float* o_C     = out + (size_t)6291456;       // [16,512,512]
    float* o_neigh = out + (size_t)10485760;      // [16,512,512]
    float* o_attn  = out + (size_t)14680064;      // [8192,768]

    float* buf0 = (float*)d_ws;                   // h -> q -> inter chunk
    float* buf1 = buf0 + (size_t)6291456;         // qg -> k
    float* buf2 = buf1 + (size_t)6291456;         // kg -> v
    float* smU  = buf2 + (size_t)6291456;
    float* smD  = smU + 8192;
    float* Ppre = smD + 8192;
    int*   emptyF = (int*)(Ppre + 8192);

    dim3 gg(12, 64);   // N/64 x M/128

    // ---- group attention ----
    ln_kernel<<<8192, 256, 0, stream>>>(x, glng, glnb, buf0);
    gemm_kernel<0><<<gg, 256, 0, stream>>>(buf0, gWq, gbq, nullptr, buf1, 768);
    gemm_kernel<0><<<gg, 256, 0, stream>>>(buf0, gWk, gbk, nullptr, buf2, 768);
    group_scores_kernel<<<8192, 256, 0, stream>>>(buf1, buf2, am, smU, smD, emptyF);
    neigh_kernel<<<8192, 512, 0, stream>>>(prior, smU, smD, emptyF, o_neigh);
    prefix_kernel<<<16, 64, 0, stream>>>(o_neigh, Ppre);
    cfill_kernel<<<8192, 512, 0, stream>>>(Ppre, o_neigh, o_C);

    // ---- multi-head attention ----
    gemm_kernel<0><<<gg, 256, 0, stream>>>(x, Wq, bq, nullptr, buf0, 768);
    gemm_kernel<0><<<gg, 256, 0, stream>>>(x, Wk, bk, nullptr, buf1, 768);
    gemm_kernel<0><<<gg, 256, 0, stream>>>(x, Wv, bv, nullptr, buf2, 768);
    mha_kernel<<<6144, 256, 0, stream>>>(buf0, buf1, buf2, am, o_C, o_layer);
    gemm_kernel<0><<<gg, 256, 0, stream>>>(o_layer, Wo, bo, nullptr, o_attn, 768);

    // ---- FFN, chunked over DI (4 x 768) to bound workspace ----
    for (int c = 0; c < 4; ++c) {
        gemm_kernel<1><<<gg, 256, 0, stream>>>(o_attn, Wi + (size_t)c * 768,
                                               bi + (size_t)c * 768, nullptr, buf0, 3072);
        if (c == 0)
            gemm_kernel<2><<<gg, 256, 0, stream>>>(buf0, Wout + (size_t)c * 768 * 768,
                                                   bout, o_attn, o_layer, 768);
        else
            gemm_kernel<3><<<gg, 256, 0, stream>>>(buf0, Wout + (size_t)c * 768 * 768,
                                                   nullptr, nullptr, o_layer, 768);
    }
    ln_kernel<<<8192, 256, 0, stream>>>(o_layer, lng, lnb, o_layer);
}

// Round 2
// 677.773 us; speedup vs baseline: 3.6970x; 3.6970x over previous
//
#include <hip/hip_runtime.h>
#include <math.h>

typedef unsigned short ushort_t;
typedef __attribute__((ext_vector_type(8))) short bf16x8;
typedef __attribute__((ext_vector_type(4))) float f32x4;

#define Dt 768
#define DIt 3072
#define Mrows 8192

__device__ __forceinline__ ushort_t f2b(float f) {
    union { float f; unsigned int u; } v; v.f = f;
    unsigned int u = v.u;
    unsigned int r = (u + 0x7fffu + ((u >> 16) & 1u)) >> 16;
    return (ushort_t)r;
}
__device__ __forceinline__ float b2f(ushort_t u) {
    union { unsigned int u; float f; } v; v.u = ((unsigned int)u) << 16;
    return v.f;
}
__device__ __forceinline__ f32x4 mfma16(bf16x8 a, bf16x8 b, f32x4 c) {
    return __builtin_amdgcn_mfma_f32_16x16x32_bf16(a, b, c, 0, 0, 0);
}
__device__ __forceinline__ float gelu_exact(float v) {
    return 0.5f * v * (1.0f + erff(v * 0.70710678118654752f));
}

// ---------------- weight transpose+convert: in f32 [K][N] -> out bf16 [N][K] ----
__global__ __launch_bounds__(256)
void tconv_kernel(const float* __restrict__ in, ushort_t* __restrict__ out,
                  int K, int N)
{
    __shared__ float T[32][33];
    int t = threadIdx.x;
    int n0 = blockIdx.x * 32, k0 = blockIdx.y * 32;
    int r = t >> 3, c4 = (t & 7) * 4;
    float4 v = *(const float4*)(in + (size_t)(k0 + r) * N + n0 + c4);
    T[r][c4] = v.x; T[r][c4 + 1] = v.y; T[r][c4 + 2] = v.z; T[r][c4 + 3] = v.w;
    __syncthreads();
    int nl = t >> 3, k4 = (t & 7) * 4;
    unsigned int lo = (unsigned int)f2b(T[k4][nl]) | ((unsigned int)f2b(T[k4 + 1][nl]) << 16);
    unsigned int hi = (unsigned int)f2b(T[k4 + 2][nl]) | ((unsigned int)f2b(T[k4 + 3][nl]) << 16);
    uint2 o; o.x = lo; o.y = hi;
    *(uint2*)(out + (size_t)(n0 + nl) * K + k0 + k4) = o;
}

// ---------------- f32 -> bf16 elementwise convert ----------------
__global__ __launch_bounds__(256)
void xconv_kernel(const float* __restrict__ in, ushort_t* __restrict__ out, int n4)
{
    int gid = blockIdx.x * 256 + threadIdx.x;
    if (gid >= n4) return;
    float4 v = ((const float4*)in)[gid];
    unsigned int lo = (unsigned int)f2b(v.x) | ((unsigned int)f2b(v.y) << 16);
    unsigned int hi = (unsigned int)f2b(v.z) | ((unsigned int)f2b(v.w) << 16);
    uint2 o; o.x = lo; o.y = hi;
    *(uint2*)(out + (size_t)gid * 4) = o;
}

// ---------------- LayerNorm (f32 math), templated output dtype ----------------
template<int BF16OUT>
__global__ __launch_bounds__(256)
void ln_kernel(const float* __restrict__ x, const float* __restrict__ g,
               const float* __restrict__ be, void* __restrict__ outv)
{
    int row = blockIdx.x;
    const float* xr = x + (size_t)row * Dt;
    int t = threadIdx.x;
    float v0 = xr[t], v1 = xr[t + 256], v2 = xr[t + 512];
    float s = v0 + v1 + v2;
    #pragma unroll
    for (int off = 32; off; off >>= 1) s += __shfl_xor(s, off, 64);
    __shared__ float r1[4], r2[4];
    if ((t & 63) == 0) r1[t >> 6] = s;
    __syncthreads();
    float mu = (r1[0] + r1[1] + r1[2] + r1[3]) * (1.0f / Dt);
    float d0 = v0 - mu, d1 = v1 - mu, d2 = v2 - mu;
    float sq = d0 * d0 + d1 * d1 + d2 * d2;
    #pragma unroll
    for (int off = 32; off; off >>= 1) sq += __shfl_xor(sq, off, 64);
    if ((t & 63) == 0) r2[t >> 6] = sq;
    __syncthreads();
    float var = (r2[0] + r2[1] + r2[2] + r2[3]) * (1.0f / Dt);
    float rs = 1.0f / sqrtf(var + 1e-12f);
    float o0 = d0 * rs * g[t]       + be[t];
    float o1 = d1 * rs * g[t + 256] + be[t + 256];
    float o2 = d2 * rs * g[t + 512] + be[t + 512];
    if (BF16OUT) {
        ushort_t* orow = (ushort_t*)outv + (size_t)row * Dt;
        orow[t] = f2b(o0); orow[t + 256] = f2b(o1); orow[t + 512] = f2b(o2);
    } else {
        float* orow = (float*)outv + (size_t)row * Dt;
        orow[t] = o0; orow[t + 256] = o1; orow[t + 512] = o2;
    }
}

// ---------------- bf16 MFMA GEMM ----------------
// C[M, N] = A[M, K](bf16,row-major,lda=K) @ Bt[N, K](bf16,row-major,ldb)^T
// BM=128, BN template (64 or 128), BK=32, 256 threads (4 waves).
enum { EPI_BF16 = 1, EPI_QSCALE = 2, EPI_BF16T = 3, EPI_DUAL = 4,
       EPI_GELU = 5, EPI_RES = 6, EPI_ACC = 7 };

template<int BN, int EPI>
__global__ __launch_bounds__(256)
void gemm_bf16(const ushort_t* __restrict__ A, const ushort_t* __restrict__ Bt,
               const float* __restrict__ bias, const float* __restrict__ res,
               float* __restrict__ Cf, ushort_t* __restrict__ Cb,
               int K, int ldb, int ldc)
{
    constexpr int WGN = BN / 64;          // waves along N: 1 or 2
    constexpr int WGM = 4 / WGN;          // waves along M: 4 or 2
    constexpr int MF  = 128 / (WGM * 16); // m-frags per wave: 2 or 4
    __shared__ ushort_t As[128][40];
    __shared__ ushort_t Bs[BN][40];
    int t = threadIdx.x;
    int w = t >> 6, l = t & 63;
    int wr = w / WGN, wc = w % WGN;
    int lr = l & 15, lg = l >> 4;
    int kb8 = lg << 3;
    int bn = blockIdx.x * BN;
    int bm = blockIdx.y * 128;

    f32x4 acc[MF][4];
    #pragma unroll
    for (int m = 0; m < MF; ++m)
        #pragma unroll
        for (int n = 0; n < 4; ++n) acc[m][n] = (f32x4)0.0f;

    for (int k0 = 0; k0 < K; k0 += 32) {
        // stage A tile 128x32 (2 chunks of 16B per thread)
        #pragma unroll
        for (int i = 0; i < 2; ++i) {
            int c = t + i * 256;
            int r = c >> 2, kc = (c & 3) << 3;
            uint4 v = *(const uint4*)(A + (size_t)(bm + r) * K + k0 + kc);
            *(uint4*)&As[r][kc] = v;
        }
        // stage B tile BNx32
        #pragma unroll
        for (int i = 0; i < BN / 64; ++i) {
            int c = t + i * 256;
            int r = c >> 2, kc = (c & 3) << 3;
            uint4 v = *(const uint4*)(Bt + (size_t)(bn + r) * ldb + k0 + kc);
            *(uint4*)&Bs[r][kc] = v;
        }
        __syncthreads();
        bf16x8 af[MF], bfr[4];
        #pragma unroll
        for (int m = 0; m < MF; ++m)
            af[m] = *(const bf16x8*)&As[wr * (MF * 16) + m * 16 + lr][kb8];
        #pragma unroll
        for (int n = 0; n < 4; ++n)
            bfr[n] = *(const bf16x8*)&Bs[wc * 64 + n * 16 + lr][kb8];
        #pragma unroll
        for (int m = 0; m < MF; ++m)
            #pragma unroll
            for (int n = 0; n < 4; ++n)
                acc[m][n] = mfma16(af[m], bfr[n], acc[m][n]);
        __syncthreads();
    }

    float biasv[4];
    if (EPI != EPI_ACC) {
        #pragma unroll
        for (int n = 0; n < 4; ++n) biasv[n] = bias[bn + wc * 64 + n * 16 + lr];
    }
    #pragma unroll
    for (int m = 0; m < MF; ++m) {
        #pragma unroll
        for (int n = 0; n < 4; ++n) {
            int mg = bm + wr * (MF * 16) + m * 16 + lg * 4;
            int ng = bn + wc * 64 + n * 16 + lr;
            #pragma unroll
            for (int r = 0; r < 4; ++r) {
                float val = acc[m][n][r];
                int row = mg + r;
                if (EPI != EPI_ACC) val += biasv[n];
                if (EPI == EPI_BF16) {
                    Cb[(size_t)row * ldc + ng] = f2b(val);
                } else if (EPI == EPI_QSCALE) {
                    Cb[(size_t)row * ldc + ng] = f2b(val * 0.125f);
                } else if (EPI == EPI_BF16T) {
                    Cb[(size_t)ng * ldc + row] = f2b(val);
                } else if (EPI == EPI_DUAL) {
                    Cf[(size_t)row * ldc + ng] = val;
                    Cb[(size_t)row * ldc + ng] = f2b(val);
                } else if (EPI == EPI_GELU) {
                    Cb[(size_t)row * ldc + ng] = f2b(gelu_exact(val));
                } else if (EPI == EPI_RES) {
                    Cf[(size_t)row * ldc + ng] = val + res[(size_t)row * Dt + ng];
                } else if (EPI == EPI_ACC) {
                    Cf[(size_t)row * ldc + ng] += val;
                }
            }
        }
    }
}

// ---------------- group attention small kernels ----------------
__global__ __launch_bounds__(256)
void group_scores_kernel(const ushort_t* __restrict__ qg, const ushort_t* __restrict__ kg,
                         const int* __restrict__ am,
                         float* __restrict__ smU, float* __restrict__ smD,
                         int* __restrict__ emptyF)
{
    int gi = blockIdx.x;
    int b = gi >> 9, s = gi & 511;
    int t = threadIdx.x;
    const ushort_t* qr = qg + (size_t)gi * Dt;
    bool hasU = (s < 511) && (am[(b << 9) + s + 1] != 0);
    bool hasD = (s > 0)   && (am[(b << 9) + s - 1] != 0);
    float su = 0.0f, sd = 0.0f;
    if (hasU) {
        const ushort_t* kr = kg + (size_t)(gi + 1) * Dt;
        for (int c = t; c < Dt; c += 256) su += b2f(qr[c]) * b2f(kr[c]);
    }
    if (hasD) {
        const ushort_t* kr = kg + (size_t)(gi - 1) * Dt;
        for (int c = t; c < Dt; c += 256) sd += b2f(qr[c]) * b2f(kr[c]);
    }
    #pragma unroll
    for (int off = 32; off; off >>= 1) { su += __shfl_xor(su, off, 64); sd += __shfl_xor(sd, off, 64); }
    __shared__ float rU[4], rD[4];
    if ((t & 63) == 0) { rU[t >> 6] = su; rD[t >> 6] = sd; }
    __syncthreads();
    if (t == 0) {
        su = (rU[0] + rU[1] + rU[2] + rU[3]) * (1.0f / Dt);
        sd = (rD[0] + rD[1] + rD[2] + rD[3]) * (1.0f / Dt);
        float u, d2; int emp = 0;
        if (hasU && hasD) {
            float m = fmaxf(su, sd);
            float eu = __expf(su - m), ed = __expf(sd - m);
            float inv = 1.0f / (eu + ed);
            u = eu * inv; d2 = ed * inv;
        } else if (hasU) { u = 1.0f; d2 = 0.0f; }
        else if (hasD)   { u = 0.0f; d2 = 1.0f; }
        else { u = d2 = 1.0f / 512.0f; emp = 1; }
        smU[gi] = u; smD[gi] = d2; emptyF[gi] = emp;
    }
}

__global__ __launch_bounds__(512)
void neigh_kernel(const float* __restrict__ prior,
                  const float* __restrict__ smU, const float* __restrict__ smD,
                  const int* __restrict__ emptyF, float* __restrict__ ne_out)
{
    int bi = blockIdx.x;
    int j  = threadIdx.x;
    int b = bi >> 9, i = bi & 511;
    int bj = (b << 9) + j;
    const float invS = 1.0f / 512.0f;
    float fij, fji;
    if (j == i + 1)      { fij = smU[bi]; fji = smD[bj]; }
    else if (j == i - 1) { fij = smD[bi]; fji = smU[bj]; }
    else { fij = emptyF[bi] ? invS : 0.0f; fji = emptyF[bj] ? invS : 0.0f; }
    float val = sqrtf(fij * fji + 1e-9f);
    float pr = prior[(size_t)bi * 512 + j];
    ne_out[(size_t)bi * 512 + j] = pr + (1.0f - pr) * val;
}

__global__ __launch_bounds__(64)
void prefix_kernel(const float* __restrict__ ne, float* __restrict__ P)
{
    int b = blockIdx.x;
    int l = threadIdx.x;
    float lv[8];
    float run = 0.0f;
    #pragma unroll
    for (int e = 0; e < 8; ++e) {
        int j = l * 8 + e;
        float lj = 0.0f;
        if (j < 511) lj = logf(ne[((size_t)(b * 512 + j)) * 512 + (j + 1)] + 1e-9f);
        lv[e] = run;
        run += lj;
    }
    float tot = run;
    float scan = tot;
    #pragma unroll
    for (int off = 1; off < 64; off <<= 1) {
        float n = __shfl_up(scan, off, 64);
        if (l >= off) scan += n;
    }
    float excl = scan - tot;
    #pragma unroll
    for (int e = 0; e < 8; ++e)
        P[b * 512 + l * 8 + e] = excl + lv[e];
}

__global__ __launch_bounds__(512)
void cfill_kernel(const float* __restrict__ P, const float* __restrict__ ne,
                  float* __restrict__ C_out)
{
    int bi = blockIdx.x;
    int j = threadIdx.x;
    int b = bi >> 9, i = bi & 511;
    float pi = P[bi], pj = P[(b << 9) + j];
    float v;
    if (j > i)      v = expf(pj - pi) + 1e-9f;
    else if (j < i) v = expf(pi - pj) + 1e-9f;
    else            v = ne[(size_t)bi * 512 + i];
    C_out[(size_t)bi * 512 + j] = v;
}

// ---------------- MFMA flash MHA: block = (qtile 64, head, batch) ----------------
// q pre-scaled by 0.125. vt is V^T global [768][8192]. out ctx bf16 [8192][768].
__global__ __launch_bounds__(256)
void mha_mfma(const ushort_t* __restrict__ q, const ushort_t* __restrict__ k,
              const ushort_t* __restrict__ vt, const int* __restrict__ am,
              const float* __restrict__ Cmat, ushort_t* __restrict__ ctx)
{
    __shared__ ushort_t Qs[64][72];
    __shared__ ushort_t Ks[64][72];
    __shared__ ushort_t Vs[64][72];   // stored as [dk][key]
    __shared__ ushort_t Ps[64][72];
    int t = threadIdx.x;
    int w = t >> 6, l = t & 63;
    int lr = l & 15, lg = l >> 4;
    int kb8 = lg << 3;
    int qt = blockIdx.x, h = blockIdx.y, b = blockIdx.z;
    int hoff = h * 64;
    int q0 = qt * 64;
    int q0g = (b << 9) + q0;

    // stage Q tile [64][64]
    #pragma unroll
    for (int i = 0; i < 2; ++i) {
        int c = t + i * 256;
        int r = c >> 3, dc = (c & 7) << 3;
        *(uint4*)&Qs[r][dc] = *(const uint4*)(q + (size_t)(q0g + r) * Dt + hoff + dc);
    }

    f32x4 oacc[4];
    #pragma unroll
    for (int n = 0; n < 4; ++n) oacc[n] = (f32x4)0.0f;
    float m_run[4], l_run[4];
    #pragma unroll
    for (int r = 0; r < 4; ++r) { m_run[r] = -3.0e38f; l_run[r] = 0.0f; }

    for (int kb = 0; kb < 8; ++kb) {
        __syncthreads();
        // stage K tile [key][dk] and V^T tile [dk][key]
        #pragma unroll
        for (int i = 0; i < 2; ++i) {
            int c = t + i * 256;
            int r = c >> 3, dc = (c & 7) << 3;
            *(uint4*)&Ks[r][dc] =
                *(const uint4*)(k + (size_t)((b << 9) + kb * 64 + r) * Dt + hoff + dc);
            *(uint4*)&Vs[r][dc] =
                *(const uint4*)(vt + (size_t)(hoff + r) * Mrows + (b << 9) + kb * 64 + dc);
        }
        __syncthreads();

        // QK^T: wave w computes rows [w*16, w*16+16) x 64 keys
        f32x4 s[4];
        #pragma unroll
        for (int n = 0; n < 4; ++n) s[n] = (f32x4)0.0f;
        #pragma unroll
        for (int ks = 0; ks < 2; ++ks) {
            bf16x8 aq = *(const bf16x8*)&Qs[w * 16 + lr][ks * 32 + kb8];
            #pragma unroll
            for (int n = 0; n < 4; ++n) {
                bf16x8 bk = *(const bf16x8*)&Ks[n * 16 + lr][ks * 32 + kb8];
                s[n] = mfma16(aq, bk, s[n]);
            }
        }
        // mask
        int amv[4];
        #pragma unroll
        for (int n = 0; n < 4; ++n) amv[n] = am[(b << 9) + kb * 64 + n * 16 + lr];
        float sv[4][4];
        #pragma unroll
        for (int n = 0; n < 4; ++n) {
            int key = kb * 64 + n * 16 + lr;
            #pragma unroll
            for (int r = 0; r < 4; ++r) {
                int qrow = q0 + w * 16 + lg * 4 + r;
                bool ok = (amv[n] != 0) || (key == qrow);
                sv[n][r] = ok ? s[n][r] : -1.0e9f;
            }
        }
        // online softmax update
        float alpha[4], rs[4];
        #pragma unroll
        for (int r = 0; r < 4; ++r) {
            float mb = fmaxf(fmaxf(sv[0][r], sv[1][r]), fmaxf(sv[2][r], sv[3][r]));
            #pragma unroll
            for (int off = 1; off < 16; off <<= 1) mb = fmaxf(mb, __shfl_xor(mb, off, 64));
            float mn = fmaxf(m_run[r], mb);
            alpha[r] = __expf(m_run[r] - mn);
            m_run[r] = mn;
            rs[r] = 0.0f;
        }
        float pf[4][4];
        #pragma unroll
        for (int n = 0; n < 4; ++n)
            #pragma unroll
            for (int r = 0; r < 4; ++r) {
                float p = __expf(sv[n][r] - m_run[r]);
                pf[n][r] = p;
                rs[r] += p;
            }
        #pragma unroll
        for (int r = 0; r < 4; ++r) {
            #pragma unroll
            for (int off = 1; off < 16; off <<= 1) rs[r] += __shfl_xor(rs[r], off, 64);
            l_run[r] = l_run[r] * alpha[r] + rs[r];
        }
        // p *= C, write to Ps (own wave's 16 rows), rescale O
        #pragma unroll
        for (int n = 0; n < 4; ++n)
            #pragma unroll
            for (int r = 0; r < 4; ++r) {
                float cc = Cmat[(size_t)(q0g + w * 16 + lg * 4 + r) * 512 + kb * 64 + n * 16 + lr];
                Ps[w * 16 + lg * 4 + r][n * 16 + lr] = f2b(pf[n][r] * cc);
            }
        #pragma unroll
        for (int n = 0; n < 4; ++n)
            #pragma unroll
            for (int r = 0; r < 4; ++r) oacc[n][r] *= alpha[r];
        // PV: oacc += P[16 x 64keys] @ V[64keys x 64dk]
        #pragma unroll
        for (int ks = 0; ks < 2; ++ks) {
            bf16x8 ap = *(const bf16x8*)&Ps[w * 16 + lr][ks * 32 + kb8];
            #pragma unroll
            for (int n = 0; n < 4; ++n) {
                bf16x8 bv = *(const bf16x8*)&Vs[n * 16 + lr][ks * 32 + kb8];
                oacc[n] = mfma16(ap, bv, oacc[n]);
            }
        }
    }
    // epilogue: divide by l, write bf16 ctx
    #pragma unroll
    for (int r = 0; r < 4; ++r) {
        float inv = 1.0f / l_run[r];
        #pragma unroll
        for (int n = 0; n < 4; ++n)
            ctx[(size_t)(q0g + w * 16 + lg * 4 + r) * Dt + hoff + n * 16 + lr] =
                f2b(oacc[n][r] * inv);
    }
}

// -----------------------------------------------------------------------------------
extern "C" void kernel_launch(void* const* d_in, const int* in_sizes, int n_in,
                              void* d_out, int out_size, void* d_ws, size_t ws_size,
                              hipStream_t stream)
{
    (void)in_sizes; (void)n_in; (void)out_size; (void)ws_size;
    const float* x     = (const float*)d_in[0];
    const float* prior = (const float*)d_in[1];
    const int*   am    = (const int*)  d_in[2];
    const float* Wq = (const float*)d_in[3];   const float* bq = (const float*)d_in[4];
    const float* Wk = (const float*)d_in[5];   const float* bk = (const float*)d_in[6];
    const float* Wv = (const float*)d_in[7];   const float* bv = (const float*)d_in[8];
    const float* Wo = (const float*)d_in[9];   const float* bo = (const float*)d_in[10];
    const float* gWk = (const float*)d_in[11]; const float* gbk = (const float*)d_in[12];
    const float* gWq = (const float*)d_in[13]; const float* gbq = (const float*)d_in[14];
    const float* glng = (const float*)d_in[15]; const float* glnb = (const float*)d_in[16];
    const float* Wi = (const float*)d_in[17];  const float* bi = (const float*)d_in[18];
    const float* Wout = (const float*)d_in[19]; const float* bout = (const float*)d_in[20];
    const float* lng = (const float*)d_in[21]; const float* lnb = (const float*)d_in[22];

    float* out = (float*)d_out;
    float* o_layer = out;                         // [8192,768] (y scratch + final)
    float* o_C     = out + (size_t)6291456;       // [16,512,512]
    float* o_neigh = out + (size_t)10485760;      // [16,512,512]
    float* o_attn  = out + (size_t)14680064;      // [8192,768]

    // ---- workspace layout (bytes) ----
    char* base = (char*)d_ws;
    ushort_t* Wqt   = (ushort_t*)(base);                     // [768][768]
    ushort_t* Wkt   = Wqt + 589824;
    ushort_t* Wvt   = Wkt + 589824;
    ushort_t* Wot   = Wvt + 589824;
    ushort_t* gWqt  = Wot + 589824;
    ushort_t* gWkt  = gWqt + 589824;
    ushort_t* Wit   = gWkt + 589824;                         // [3072][768]
    ushort_t* Woutt = Wit + 2359296;                         // [768][3072]
    // end of weights @ 16515072 B
    ushort_t* XB    = (ushort_t*)(base + 16515072);          // [8192][768] bf16
    ushort_t* HB    = (ushort_t*)(base + 29097984);
    ushort_t* QGB   = (ushort_t*)(base + 41680896);
    ushort_t* KGB   = (ushort_t*)(base + 54263808);
    float*    smU   = (float*)(base + 66846720);
    float*    smD   = smU + 8192;
    float*    Ppre  = smD + 8192;
    int*      emptyF= (int*)(Ppre + 8192);
    // aliases (lifetimes disjoint)
    ushort_t* QB    = HB;                                    // after gW gemms
    ushort_t* KB    = QGB;
    ushort_t* VT    = KGB;                                   // [768][8192]
    ushort_t* CTXB  = XB;                                    // after qkv gemms
    ushort_t* AB16  = HB;                                    // after mha
    ushort_t* INTERC= QGB;                                   // [8192][1536] after mha

    // ---- weight transposes (bf16) ----
    tconv_kernel<<<dim3(24, 24), 256, 0, stream>>>(Wq, Wqt, 768, 768);
    tconv_kernel<<<dim3(24, 24), 256, 0, stream>>>(Wk, Wkt, 768, 768);
    tconv_kernel<<<dim3(24, 24), 256, 0, stream>>>(Wv, Wvt, 768, 768);
    tconv_kernel<<<dim3(24, 24), 256, 0, stream>>>(Wo, Wot, 768, 768);
    tconv_kernel<<<dim3(24, 24), 256, 0, stream>>>(gWq, gWqt, 768, 768);
    tconv_kernel<<<dim3(24, 24), 256, 0, stream>>>(gWk, gWkt, 768, 768);
    tconv_kernel<<<dim3(96, 24), 256, 0, stream>>>(Wi, Wit, 768, 3072);
    tconv_kernel<<<dim3(24, 96), 256, 0, stream>>>(Wout, Woutt, 3072, 768);
    xconv_kernel<<<6144, 256, 0, stream>>>(x, XB, 1572864);

    // ---- group attention ----
    ln_kernel<1><<<8192, 256, 0, stream>>>(x, glng, glnb, HB);
    gemm_bf16<64, EPI_BF16><<<dim3(12, 64), 256, 0, stream>>>(HB, gWqt, gbq, nullptr, nullptr, QGB, 768, 768, 768);
    gemm_bf16<64, EPI_BF16><<<dim3(12, 64), 256, 0, stream>>>(HB, gWkt, gbk, nullptr, nullptr, KGB, 768, 768, 768);
    group_scores_kernel<<<8192, 256, 0, stream>>>(QGB, KGB, am, smU, smD, emptyF);
    neigh_kernel<<<8192, 512, 0, stream>>>(prior, smU, smD, emptyF, o_neigh);
    prefix_kernel<<<16, 64, 0, stream>>>(o_neigh, Ppre);
    cfill_kernel<<<8192, 512, 0, stream>>>(Ppre, o_neigh, o_C);

    // ---- multi-head attention ----
    gemm_bf16<64, EPI_QSCALE><<<dim3(12, 64), 256, 0, stream>>>(XB, Wqt, bq, nullptr, nullptr, QB, 768, 768, 768);
    gemm_bf16<64, EPI_BF16><<<dim3(12, 64), 256, 0, stream>>>(XB, Wkt, bk, nullptr, nullptr, KB, 768, 768, 768);
    gemm_bf16<64, EPI_BF16T><<<dim3(12, 64), 256, 0, stream>>>(XB, Wvt, bv, nullptr, nullptr, VT, 768, 768, 8192);
    mha_mfma<<<dim3(8, 12, 16), 256, 0, stream>>>(QB, KB, VT, am, o_C, CTXB);
    gemm_bf16<64, EPI_DUAL><<<dim3(12, 64), 256, 0, stream>>>(CTXB, Wot, bo, nullptr, o_attn, AB16, 768, 768, 768);

    // ---- FFN, 2 chunks of 1536 over DI ----
    for (int c = 0; c < 2; ++c) {
        gemm_bf16<128, EPI_GELU><<<dim3(12, 64), 256, 0, stream>>>(
            AB16, Wit + (size_t)c * 1536 * 768, bi + (size_t)c * 1536, nullptr,
            nullptr, INTERC, 768, 768, 1536);
        if (c == 0)
            gemm_bf16<64, EPI_RES><<<dim3(12, 64), 256, 0, stream>>>(
                INTERC, Woutt + (size_t)c * 1536, bout, o_attn, o_layer, nullptr,
                1536, 3072, 768);
        else
            gemm_bf16<64, EPI_ACC><<<dim3(12, 64), 256, 0, stream>>>(
                INTERC, Woutt + (size_t)c * 1536, nullptr, nullptr, o_layer, nullptr,
                1536, 3072, 768);
    }
    ln_kernel<0><<<8192, 256, 0, stream>>>(o_layer, lng, lnb, o_layer);
}

// Round 3
// 571.982 us; speedup vs baseline: 4.3808x; 1.1850x over previous
//
#include <hip/hip_runtime.h>
#include <math.h>

typedef unsigned short ushort_t;
typedef __attribute__((ext_vector_type(8))) short bf16x8;
typedef __attribute__((ext_vector_type(4))) float f32x4;

#define Dt 768
#define Mrows 8192

__device__ __forceinline__ ushort_t f2b(float f) {
    union { float f; unsigned int u; } v; v.f = f;
    unsigned int u = v.u;
    unsigned int r = (u + 0x7fffu + ((u >> 16) & 1u)) >> 16;
    return (ushort_t)r;
}
__device__ __forceinline__ float b2f(ushort_t u) {
    union { unsigned int u; float f; } v; v.u = ((unsigned int)u) << 16;
    return v.f;
}
__device__ __forceinline__ f32x4 mfma16(bf16x8 a, bf16x8 b, f32x4 c) {
    return __builtin_amdgcn_mfma_f32_16x16x32_bf16(a, b, c, 0, 0, 0);
}
__device__ __forceinline__ float gelu_exact(float v) {
    return 0.5f * v * (1.0f + erff(v * 0.70710678118654752f));
}
__device__ __forceinline__ void gl2lds16(const ushort_t* g, ushort_t* l) {
    __builtin_amdgcn_global_load_lds((const __attribute__((address_space(1))) void*)g,
                                     (__attribute__((address_space(3))) void*)l,
                                     16, 0, 0);
}

// ---------------- weight transpose+convert: in f32 [K][N] -> out bf16 [N][K] ----
__global__ __launch_bounds__(256)
void tconv_kernel(const float* __restrict__ in, ushort_t* __restrict__ out,
                  int K, int N)
{
    __shared__ float T[32][33];
    int t = threadIdx.x;
    int n0 = blockIdx.x * 32, k0 = blockIdx.y * 32;
    int r = t >> 3, c4 = (t & 7) * 4;
    float4 v = *(const float4*)(in + (size_t)(k0 + r) * N + n0 + c4);
    T[r][c4] = v.x; T[r][c4 + 1] = v.y; T[r][c4 + 2] = v.z; T[r][c4 + 3] = v.w;
    __syncthreads();
    int nl = t >> 3, k4 = (t & 7) * 4;
    unsigned int lo = (unsigned int)f2b(T[k4][nl]) | ((unsigned int)f2b(T[k4 + 1][nl]) << 16);
    unsigned int hi = (unsigned int)f2b(T[k4 + 2][nl]) | ((unsigned int)f2b(T[k4 + 3][nl]) << 16);
    uint2 o; o.x = lo; o.y = hi;
    *(uint2*)(out + (size_t)(n0 + nl) * K + k0 + k4) = o;
}

// ---------------- f32 -> bf16 elementwise convert ----------------
__global__ __launch_bounds__(256)
void xconv_kernel(const float* __restrict__ in, ushort_t* __restrict__ out, int n4)
{
    int gid = blockIdx.x * 256 + threadIdx.x;
    if (gid >= n4) return;
    float4 v = ((const float4*)in)[gid];
    unsigned int lo = (unsigned int)f2b(v.x) | ((unsigned int)f2b(v.y) << 16);
    unsigned int hi = (unsigned int)f2b(v.z) | ((unsigned int)f2b(v.w) << 16);
    uint2 o; o.x = lo; o.y = hi;
    *(uint2*)(out + (size_t)gid * 4) = o;
}

// ---------------- bias concatenation ----------------
__global__ __launch_bounds__(256)
void bconcat_kernel(const float* bq, const float* bk, const float* bv,
                    const float* gbq, const float* gbk,
                    float* bqkv, float* gbqk)
{
    int g = blockIdx.x * 256 + threadIdx.x;
    if (g < 768)       bqkv[g] = bq[g];
    else if (g < 1536) bqkv[g] = bk[g - 768];
    else if (g < 2304) bqkv[g] = bv[g - 1536];
    else if (g < 3072) gbqk[g - 2304] = gbq[g - 2304];
    else if (g < 3840) gbqk[g - 2304] = gbk[g - 3072];
}

// ---------------- LayerNorm (f32 math), templated output dtype ----------------
template<int BF16OUT>
__global__ __launch_bounds__(256)
void ln_kernel(const float* __restrict__ x, const float* __restrict__ g,
               const float* __restrict__ be, void* __restrict__ outv)
{
    int row = blockIdx.x;
    const float* xr = x + (size_t)row * Dt;
    int t = threadIdx.x;
    float v0 = xr[t], v1 = xr[t + 256], v2 = xr[t + 512];
    float s = v0 + v1 + v2;
    #pragma unroll
    for (int off = 32; off; off >>= 1) s += __shfl_xor(s, off, 64);
    __shared__ float r1[4], r2[4];
    if ((t & 63) == 0) r1[t >> 6] = s;
    __syncthreads();
    float mu = (r1[0] + r1[1] + r1[2] + r1[3]) * (1.0f / Dt);
    float d0 = v0 - mu, d1 = v1 - mu, d2 = v2 - mu;
    float sq = d0 * d0 + d1 * d1 + d2 * d2;
    #pragma unroll
    for (int off = 32; off; off >>= 1) sq += __shfl_xor(sq, off, 64);
    if ((t & 63) == 0) r2[t >> 6] = sq;
    __syncthreads();
    float var = (r2[0] + r2[1] + r2[2] + r2[3]) * (1.0f / Dt);
    float rs = 1.0f / sqrtf(var + 1e-12f);
    float o0 = d0 * rs * g[t]       + be[t];
    float o1 = d1 * rs * g[t + 256] + be[t + 256];
    float o2 = d2 * rs * g[t + 512] + be[t + 512];
    if (BF16OUT) {
        ushort_t* orow = (ushort_t*)outv + (size_t)row * Dt;
        orow[t] = f2b(o0); orow[t + 256] = f2b(o1); orow[t + 512] = f2b(o2);
    } else {
        float* orow = (float*)outv + (size_t)row * Dt;
        orow[t] = o0; orow[t + 256] = o1; orow[t + 512] = o2;
    }
}

// ---------------- bf16 MFMA GEMM, m97 structure: global_load_lds(16B) ----------------
// C[M,N] = A[M,K] @ Bt[N,K]^T.  BM=128, BN in {64,128}, BK=32, 256 thr (2x2 waves).
enum { EPI_BF16 = 1, EPI_QKV = 2, EPI_DUAL = 3, EPI_GELU = 4, EPI_RES = 5, EPI_ACC = 6 };

template<int BN, int EPI>
__global__ __launch_bounds__(256)
void gemm128(const ushort_t* __restrict__ A, const ushort_t* __restrict__ Bt,
             const float* __restrict__ bias, const float* __restrict__ res,
             float* __restrict__ Cf, ushort_t* __restrict__ O0,
             ushort_t* __restrict__ O1, ushort_t* __restrict__ O2,
             int K, int ldb, int ldc)
{
    constexpr int NF = BN / 32;             // B frags per wave (2x2 wave grid)
    __shared__ ushort_t As[128 * 32];       // linear row-major [128][32]
    __shared__ ushort_t Bs[BN * 32];
    int t = threadIdx.x;
    int w = t >> 6, l = t & 63;
    int wr = w >> 1, wc = w & 1;
    int lr = l & 15, lg = l >> 4;
    int bn = blockIdx.x * BN;
    int bm = blockIdx.y * 128;

    // staging: chunk c covers row c>>2, elem col (c&3)*8 (16B). LDS dest is
    // wave-uniform base + lane*16 (HW rule), so LDS must be linear row-major.
    const ushort_t* gA0 = A + (size_t)(bm + (t >> 2)) * K + ((t & 3) << 3);
    const ushort_t* gA1 = A + (size_t)(bm + 64 + (t >> 2)) * K + ((t & 3) << 3);
    const ushort_t* gB0 = Bt + (size_t)(bn + (t >> 2)) * ldb + ((t & 3) << 3);
    const ushort_t* gB1 = (BN == 128) ?
        Bt + (size_t)(bn + 64 + (t >> 2)) * ldb + ((t & 3) << 3) : nullptr;
    ushort_t* lA0 = As + (w << 9);          // (w*64 chunks)*8 ushorts
    ushort_t* lA1 = As + 2048 + (w << 9);
    ushort_t* lB0 = Bs + (w << 9);
    ushort_t* lB1 = Bs + 2048 + (w << 9);

    f32x4 acc[4][NF];
    #pragma unroll
    for (int m = 0; m < 4; ++m)
        #pragma unroll
        for (int n = 0; n < NF; ++n) acc[m][n] = (f32x4)0.0f;

    for (int k0 = 0; k0 < K; k0 += 32) {
        gl2lds16(gA0 + k0, lA0);
        gl2lds16(gA1 + k0, lA1);
        gl2lds16(gB0 + k0, lB0);
        if (BN == 128) gl2lds16(gB1 + k0, lB1);
        __syncthreads();                     // drains vmcnt (LDS-DMA) + barrier
        bf16x8 af[4], bfv[NF];
        #pragma unroll
        for (int m = 0; m < 4; ++m)
            af[m] = *(const bf16x8*)&As[(wr * 64 + m * 16 + lr) * 32 + lg * 8];
        #pragma unroll
        for (int n = 0; n < NF; ++n)
            bfv[n] = *(const bf16x8*)&Bs[(wc * (BN / 2) + n * 16 + lr) * 32 + lg * 8];
        __builtin_amdgcn_s_setprio(1);
        #pragma unroll
        for (int m = 0; m < 4; ++m)
            #pragma unroll
            for (int n = 0; n < NF; ++n)
                acc[m][n] = mfma16(af[m], bfv[n], acc[m][n]);
        __builtin_amdgcn_s_setprio(0);
        __syncthreads();
    }

    // epilogue. C/D frag: col = lane&15, row = (lane>>4)*4 + reg.
    #pragma unroll
    for (int m = 0; m < 4; ++m) {
        int row0 = bm + wr * 64 + m * 16 + lg * 4;
        #pragma unroll
        for (int n = 0; n < NF; ++n) {
            int ng = bn + wc * (BN / 2) + n * 16 + lr;
            float v0 = acc[m][n][0], v1 = acc[m][n][1];
            float v2 = acc[m][n][2], v3 = acc[m][n][3];
            if (EPI != EPI_ACC) {
                float bv = bias[ng];
                v0 += bv; v1 += bv; v2 += bv; v3 += bv;
            }
            if (EPI == EPI_BF16) {
                O0[(size_t)(row0 + 0) * ldc + ng] = f2b(v0);
                O0[(size_t)(row0 + 1) * ldc + ng] = f2b(v1);
                O0[(size_t)(row0 + 2) * ldc + ng] = f2b(v2);
                O0[(size_t)(row0 + 3) * ldc + ng] = f2b(v3);
            } else if (EPI == EPI_QKV) {
                if (bn < 768) {             // Q: pre-scale by 1/sqrt(dk)=0.125
                    O0[(size_t)(row0 + 0) * 768 + ng] = f2b(v0 * 0.125f);
                    O0[(size_t)(row0 + 1) * 768 + ng] = f2b(v1 * 0.125f);
                    O0[(size_t)(row0 + 2) * 768 + ng] = f2b(v2 * 0.125f);
                    O0[(size_t)(row0 + 3) * 768 + ng] = f2b(v3 * 0.125f);
                } else if (bn < 1536) {     // K
                    int c = ng - 768;
                    O1[(size_t)(row0 + 0) * 768 + c] = f2b(v0);
                    O1[(size_t)(row0 + 1) * 768 + c] = f2b(v1);
                    O1[(size_t)(row0 + 2) * 768 + c] = f2b(v2);
                    O1[(size_t)(row0 + 3) * 768 + c] = f2b(v3);
                } else {                    // V transposed: VT[dk][8192], 8B pack
                    int dk = ng - 1536;
                    unsigned int lo = (unsigned int)f2b(v0) | ((unsigned int)f2b(v1) << 16);
                    unsigned int hi = (unsigned int)f2b(v2) | ((unsigned int)f2b(v3) << 16);
                    uint2 o; o.x = lo; o.y = hi;
                    *(uint2*)(O2 + (size_t)dk * Mrows + row0) = o;
                }
            } else if (EPI == EPI_DUAL) {
                Cf[(size_t)(row0 + 0) * ldc + ng] = v0;
                Cf[(size_t)(row0 + 1) * ldc + ng] = v1;
                Cf[(size_t)(row0 + 2) * ldc + ng] = v2;
                Cf[(size_t)(row0 + 3) * ldc + ng] = v3;
                O0[(size_t)(row0 + 0) * ldc + ng] = f2b(v0);
                O0[(size_t)(row0 + 1) * ldc + ng] = f2b(v1);
                O0[(size_t)(row0 + 2) * ldc + ng] = f2b(v2);
                O0[(size_t)(row0 + 3) * ldc + ng] = f2b(v3);
            } else if (EPI == EPI_GELU) {
                O0[(size_t)(row0 + 0) * ldc + ng] = f2b(gelu_exact(v0));
                O0[(size_t)(row0 + 1) * ldc + ng] = f2b(gelu_exact(v1));
                O0[(size_t)(row0 + 2) * ldc + ng] = f2b(gelu_exact(v2));
                O0[(size_t)(row0 + 3) * ldc + ng] = f2b(gelu_exact(v3));
            } else if (EPI == EPI_RES) {
                Cf[(size_t)(row0 + 0) * ldc + ng] = v0 + res[(size_t)(row0 + 0) * Dt + ng];
                Cf[(size_t)(row0 + 1) * ldc + ng] = v1 + res[(size_t)(row0 + 1) * Dt + ng];
                Cf[(size_t)(row0 + 2) * ldc + ng] = v2 + res[(size_t)(row0 + 2) * Dt + ng];
                Cf[(size_t)(row0 + 3) * ldc + ng] = v3 + res[(size_t)(row0 + 3) * Dt + ng];
            } else if (EPI == EPI_ACC) {
                Cf[(size_t)(row0 + 0) * ldc + ng] += v0;
                Cf[(size_t)(row0 + 1) * ldc + ng] += v1;
                Cf[(size_t)(row0 + 2) * ldc + ng] += v2;
                Cf[(size_t)(row0 + 3) * ldc + ng] += v3;
            }
        }
    }
}

// ---------------- group attention small kernels ----------------
// GQK: [8192][1536] bf16, cols 0-767 = q, 768-1535 = k
__global__ __launch_bounds__(256)
void group_scores_kernel(const ushort_t* __restrict__ GQK, const int* __restrict__ am,
                         float* __restrict__ smU, float* __restrict__ smD,
                         int* __restrict__ emptyF)
{
    int gi = blockIdx.x;
    int b = gi >> 9, s = gi & 511;
    int t = threadIdx.x;
    const ushort_t* qr = GQK + (size_t)gi * 1536;
    bool hasU = (s < 511) && (am[(b << 9) + s + 1] != 0);
    bool hasD = (s > 0)   && (am[(b << 9) + s - 1] != 0);
    float su = 0.0f, sd = 0.0f;
    if (hasU) {
        const ushort_t* kr = GQK + (size_t)(gi + 1) * 1536 + 768;
        for (int c = t; c < Dt; c += 256) su += b2f(qr[c]) * b2f(kr[c]);
    }
    if (hasD) {
        const ushort_t* kr = GQK + (size_t)(gi - 1) * 1536 + 768;
        for (int c = t; c < Dt; c += 256) sd += b2f(qr[c]) * b2f(kr[c]);
    }
    #pragma unroll
    for (int off = 32; off; off >>= 1) { su += __shfl_xor(su, off, 64); sd += __shfl_xor(sd, off, 64); }
    __shared__ float rU[4], rD[4];
    if ((t & 63) == 0) { rU[t >> 6] = su; rD[t >> 6] = sd; }
    __syncthreads();
    if (t == 0) {
        su = (rU[0] + rU[1] + rU[2] + rU[3]) * (1.0f / Dt);
        sd = (rD[0] + rD[1] + rD[2] + rD[3]) * (1.0f / Dt);
        float u, d2; int emp = 0;
        if (hasU && hasD) {
            float m = fmaxf(su, sd);
            float eu = __expf(su - m), ed = __expf(sd - m);
            float inv = 1.0f / (eu + ed);
            u = eu * inv; d2 = ed * inv;
        } else if (hasU) { u = 1.0f; d2 = 0.0f; }
        else if (hasD)   { u = 0.0f; d2 = 1.0f; }
        else { u = d2 = 1.0f / 512.0f; emp = 1; }
        smU[gi] = u; smD[gi] = d2; emptyF[gi] = emp;
    }
}

__global__ __launch_bounds__(512)
void neigh_kernel(const float* __restrict__ prior,
                  const float* __restrict__ smU, const float* __restrict__ smD,
                  const int* __restrict__ emptyF, float* __restrict__ ne_out)
{
    int bi = blockIdx.x;
    int j  = threadIdx.x;
    int b = bi >> 9, i = bi & 511;
    int bj = (b << 9) + j;
    const float invS = 1.0f / 512.0f;
    float fij, fji;
    if (j == i + 1)      { fij = smU[bi]; fji = smD[bj]; }
    else if (j == i - 1) { fij = smD[bi]; fji = smU[bj]; }
    else { fij = emptyF[bi] ? invS : 0.0f; fji = emptyF[bj] ? invS : 0.0f; }
    float val = sqrtf(fij * fji + 1e-9f);
    float pr = prior[(size_t)bi * 512 + j];
    ne_out[(size_t)bi * 512 + j] = pr + (1.0f - pr) * val;
}

__global__ __launch_bounds__(64)
void prefix_kernel(const float* __restrict__ ne, float* __restrict__ P)
{
    int b = blockIdx.x;
    int l = threadIdx.x;
    float lv[8];
    float run = 0.0f;
    #pragma unroll
    for (int e = 0; e < 8; ++e) {
        int j = l * 8 + e;
        float lj = 0.0f;
        if (j < 511) lj = logf(ne[((size_t)(b * 512 + j)) * 512 + (j + 1)] + 1e-9f);
        lv[e] = run;
        run += lj;
    }
    float tot = run;
    float scan = tot;
    #pragma unroll
    for (int off = 1; off < 64; off <<= 1) {
        float n = __shfl_up(scan, off, 64);
        if (l >= off) scan += n;
    }
    float excl = scan - tot;
    #pragma unroll
    for (int e = 0; e < 8; ++e)
        P[b * 512 + l * 8 + e] = excl + lv[e];
}

__global__ __launch_bounds__(512)
void cfill_kernel(const float* __restrict__ P, const float* __restrict__ ne,
                  float* __restrict__ C_out)
{
    int bi = blockIdx.x;
    int j = threadIdx.x;
    int b = bi >> 9, i = bi & 511;
    float pi = P[bi], pj = P[(b << 9) + j];
    float v;
    if (j > i)      v = expf(pj - pi) + 1e-9f;
    else if (j < i) v = expf(pi - pj) + 1e-9f;
    else            v = ne[(size_t)bi * 512 + i];
    C_out[(size_t)bi * 512 + j] = v;
}

// ---------------- MFMA flash MHA: block = (qtile 64, head, batch) ----------------
__global__ __launch_bounds__(256)
void mha_mfma(const ushort_t* __restrict__ q, const ushort_t* __restrict__ k,
              const ushort_t* __restrict__ vt, const int* __restrict__ am,
              const float* __restrict__ Cmat, ushort_t* __restrict__ ctx)
{
    __shared__ ushort_t Qs[64][72];
    __shared__ ushort_t Ks[64][72];
    __shared__ ushort_t Vs[64][72];   // [dk][key]
    __shared__ ushort_t Ps[64][72];
    int t = threadIdx.x;
    int w = t >> 6, l = t & 63;
    int lr = l & 15, lg = l >> 4;
    int kb8 = lg << 3;
    int qt = blockIdx.x, h = blockIdx.y, b = blockIdx.z;
    int hoff = h * 64;
    int q0 = qt * 64;
    int q0g = (b << 9) + q0;

    #pragma unroll
    for (int i = 0; i < 2; ++i) {
        int c = t + i * 256;
        int r = c >> 3, dc = (c & 7) << 3;
        *(uint4*)&Qs[r][dc] = *(const uint4*)(q + (size_t)(q0g + r) * Dt + hoff + dc);
    }

    f32x4 oacc[4];
    #pragma unroll
    for (int n = 0; n < 4; ++n) oacc[n] = (f32x4)0.0f;
    float m_run[4], l_run[4];
    #pragma unroll
    for (int r = 0; r < 4; ++r) { m_run[r] = -3.0e38f; l_run[r] = 0.0f; }

    for (int kb = 0; kb < 8; ++kb) {
        __syncthreads();
        #pragma unroll
        for (int i = 0; i < 2; ++i) {
            int c = t + i * 256;
            int r = c >> 3, dc = (c & 7) << 3;
            *(uint4*)&Ks[r][dc] =
                *(const uint4*)(k + (size_t)((b << 9) + kb * 64 + r) * Dt + hoff + dc);
            *(uint4*)&Vs[r][dc] =
                *(const uint4*)(vt + (size_t)(hoff + r) * Mrows + (b << 9) + kb * 64 + dc);
        }
        __syncthreads();

        // early loads: mask + C scale factors (overlap with QK^T MFMAs)
        int amv[4];
        #pragma unroll
        for (int n = 0; n < 4; ++n) amv[n] = am[(b << 9) + kb * 64 + n * 16 + lr];
        float cc[4][4];
        #pragma unroll
        for (int n = 0; n < 4; ++n)
            #pragma unroll
            for (int r = 0; r < 4; ++r)
                cc[n][r] = Cmat[(size_t)(q0g + w * 16 + lg * 4 + r) * 512 + kb * 64 + n * 16 + lr];

        f32x4 s[4];
        #pragma unroll
        for (int n = 0; n < 4; ++n) s[n] = (f32x4)0.0f;
        __builtin_amdgcn_s_setprio(1);
        #pragma unroll
        for (int ks = 0; ks < 2; ++ks) {
            bf16x8 aq = *(const bf16x8*)&Qs[w * 16 + lr][ks * 32 + kb8];
            #pragma unroll
            for (int n = 0; n < 4; ++n) {
                bf16x8 bk = *(const bf16x8*)&Ks[n * 16 + lr][ks * 32 + kb8];
                s[n] = mfma16(aq, bk, s[n]);
            }
        }
        __builtin_amdgcn_s_setprio(0);

        float sv[4][4];
        #pragma unroll
        for (int n = 0; n < 4; ++n) {
            int key = kb * 64 + n * 16 + lr;
            #pragma unroll
            for (int r = 0; r < 4; ++r) {
                int qrow = q0 + w * 16 + lg * 4 + r;
                bool ok = (amv[n] != 0) || (key == qrow);
                sv[n][r] = ok ? s[n][r] : -1.0e9f;
            }
        }
        float alpha[4], rsum[4];
        #pragma unroll
        for (int r = 0; r < 4; ++r) {
            float mb = fmaxf(fmaxf(sv[0][r], sv[1][r]), fmaxf(sv[2][r], sv[3][r]));
            #pragma unroll
            for (int off = 1; off < 16; off <<= 1) mb = fmaxf(mb, __shfl_xor(mb, off, 64));
            float mn = fmaxf(m_run[r], mb);
            alpha[r] = __expf(m_run[r] - mn);
            m_run[r] = mn;
            rsum[r] = 0.0f;
        }
        float pf[4][4];
        #pragma unroll
        for (int n = 0; n < 4; ++n)
            #pragma unroll
            for (int r = 0; r < 4; ++r) {
                float p = __expf(sv[n][r] - m_run[r]);
                pf[n][r] = p;
                rsum[r] += p;
            }
        #pragma unroll
        for (int r = 0; r < 4; ++r) {
            #pragma unroll
            for (int off = 1; off < 16; off <<= 1) rsum[r] += __shfl_xor(rsum[r], off, 64);
            l_run[r] = l_run[r] * alpha[r] + rsum[r];
        }
        #pragma unroll
        for (int n = 0; n < 4; ++n)
            #pragma unroll
            for (int r = 0; r < 4; ++r)
                Ps[w * 16 + lg * 4 + r][n * 16 + lr] = f2b(pf[n][r] * cc[n][r]);
        #pragma unroll
        for (int n = 0; n < 4; ++n)
            #pragma unroll
            for (int r = 0; r < 4; ++r) oacc[n][r] *= alpha[r];
        __builtin_amdgcn_s_setprio(1);
        #pragma unroll
        for (int ks = 0; ks < 2; ++ks) {
            bf16x8 ap = *(const bf16x8*)&Ps[w * 16 + lr][ks * 32 + kb8];
            #pragma unroll
            for (int n = 0; n < 4; ++n) {
                bf16x8 bv = *(const bf16x8*)&Vs[n * 16 + lr][ks * 32 + kb8];
                oacc[n] = mfma16(ap, bv, oacc[n]);
            }
        }
        __builtin_amdgcn_s_setprio(0);
    }
    #pragma unroll
    for (int r = 0; r < 4; ++r) {
        float inv = 1.0f / l_run[r];
        #pragma unroll
        for (int n = 0; n < 4; ++n)
            ctx[(size_t)(q0g + w * 16 + lg * 4 + r) * Dt + hoff + n * 16 + lr] =
                f2b(oacc[n][r] * inv);
    }
}

// -----------------------------------------------------------------------------------
extern "C" void kernel_launch(void* const* d_in, const int* in_sizes, int n_in,
                              void* d_out, int out_size, void* d_ws, size_t ws_size,
                              hipStream_t stream)
{
    (void)in_sizes; (void)n_in; (void)out_size; (void)ws_size;
    const float* x     = (const float*)d_in[0];
    const float* prior = (const float*)d_in[1];
    const int*   am    = (const int*)  d_in[2];
    const float* Wq = (const float*)d_in[3];   const float* bq = (const float*)d_in[4];
    const float* Wk = (const float*)d_in[5];   const float* bk = (const float*)d_in[6];
    const float* Wv = (const float*)d_in[7];   const float* bv = (const float*)d_in[8];
    const float* Wo = (const float*)d_in[9];   const float* bo = (const float*)d_in[10];
    const float* gWk = (const float*)d_in[11]; const float* gbk = (const float*)d_in[12];
    const float* gWq = (const float*)d_in[13]; const float* gbq = (const float*)d_in[14];
    const float* glng = (const float*)d_in[15]; const float* glnb = (const float*)d_in[16];
    const float* Wi = (const float*)d_in[17];  const float* bi = (const float*)d_in[18];
    const float* Wout = (const float*)d_in[19]; const float* bout = (const float*)d_in[20];
    const float* lng = (const float*)d_in[21]; const float* lnb = (const float*)d_in[22];

    float* out = (float*)d_out;
    float* o_layer = out;
    float* o_C     = out + (size_t)6291456;
    float* o_neigh = out + (size_t)10485760;
    float* o_attn  = out + (size_t)14680064;

    // ---- workspace layout ----
    char* base = (char*)d_ws;
    ushort_t* WqkvT = (ushort_t*)(base);                  // [2304][768]
    ushort_t* gWqkT = (ushort_t*)(base + 3538944);        // [1536][768]
    ushort_t* WoT   = (ushort_t*)(base + 5898240);        // [768][768]
    ushort_t* WiT   = (ushort_t*)(base + 7077888);        // [3072][768]
    ushort_t* WoutT = (ushort_t*)(base + 11796480);       // [768][3072]
    float*    bqkv  = (float*)(base + 16515072);          // [2304]
    float*    gbqk  = (float*)(base + 16524288);          // [1536]
    float*    smU   = (float*)(base + 16530432);
    float*    smD   = (float*)(base + 16563200);
    float*    Ppre  = (float*)(base + 16595968);
    int*      emptyF= (int*)(base + 16628736);
    // phase-aliased activation slots
    ushort_t* s0 = (ushort_t*)(base + 16661504);          // 12.6 MB: XB / CTXB
    ushort_t* s1 = (ushort_t*)(base + 29244416);          // 12.6 MB: HB / QB / AB16
    ushort_t* s2 = (ushort_t*)(base + 41827328);          // 25.2 MB: GQK / KB+VT / INTER
    ushort_t* XB = s0;    ushort_t* CTXB = s0;
    ushort_t* HB = s1;    ushort_t* QB = s1;   ushort_t* AB16 = s1;
    ushort_t* GQK = s2;   ushort_t* KB = s2;   ushort_t* INTER = s2;
    ushort_t* VT = s2 + 6291456;                           // [768][8192]

    // ---- weight prep ----
    tconv_kernel<<<dim3(24, 24), 256, 0, stream>>>(Wq, WqkvT, 768, 768);
    tconv_kernel<<<dim3(24, 24), 256, 0, stream>>>(Wk, WqkvT + 589824, 768, 768);
    tconv_kernel<<<dim3(24, 24), 256, 0, stream>>>(Wv, WqkvT + 1179648, 768, 768);
    tconv_kernel<<<dim3(24, 24), 256, 0, stream>>>(gWq, gWqkT, 768, 768);
    tconv_kernel<<<dim3(24, 24), 256, 0, stream>>>(gWk, gWqkT + 589824, 768, 768);
    tconv_kernel<<<dim3(24, 24), 256, 0, stream>>>(Wo, WoT, 768, 768);
    tconv_kernel<<<dim3(96, 24), 256, 0, stream>>>(Wi, WiT, 768, 3072);
    tconv_kernel<<<dim3(24, 96), 256, 0, stream>>>(Wout, WoutT, 3072, 768);
    bconcat_kernel<<<15, 256, 0, stream>>>(bq, bk, bv, gbq, gbk, bqkv, gbqk);
    xconv_kernel<<<6144, 256, 0, stream>>>(x, XB, 1572864);

    // ---- group attention ----
    ln_kernel<1><<<8192, 256, 0, stream>>>(x, glng, glnb, HB);
    gemm128<128, EPI_BF16><<<dim3(12, 64), 256, 0, stream>>>(
        HB, gWqkT, gbqk, nullptr, nullptr, GQK, nullptr, nullptr, 768, 768, 1536);
    group_scores_kernel<<<8192, 256, 0, stream>>>(GQK, am, smU, smD, emptyF);
    neigh_kernel<<<8192, 512, 0, stream>>>(prior, smU, smD, emptyF, o_neigh);
    prefix_kernel<<<16, 64, 0, stream>>>(o_neigh, Ppre);
    cfill_kernel<<<8192, 512, 0, stream>>>(Ppre, o_neigh, o_C);

    // ---- multi-head attention ----
    gemm128<128, EPI_QKV><<<dim3(18, 64), 256, 0, stream>>>(
        XB, WqkvT, bqkv, nullptr, nullptr, QB, KB, VT, 768, 768, 768);
    mha_mfma<<<dim3(8, 12, 16), 256, 0, stream>>>(QB, KB, VT, am, o_C, CTXB);
    gemm128<64, EPI_DUAL><<<dim3(12, 64), 256, 0, stream>>>(
        CTXB, WoT, bo, nullptr, o_attn, AB16, nullptr, nullptr, 768, 768, 768);

    // ---- FFN, 2 chunks of 1536 over DI ----
    for (int c = 0; c < 2; ++c) {
        gemm128<128, EPI_GELU><<<dim3(12, 64), 256, 0, stream>>>(
            AB16, WiT + (size_t)c * 1536 * 768, bi + (size_t)c * 1536, nullptr,
            nullptr, INTER, nullptr, nullptr, 768, 768, 1536);
        if (c == 0)
            gemm128<64, EPI_RES><<<dim3(12, 64), 256, 0, stream>>>(
                INTER, WoutT + (size_t)c * 1536, bout, o_attn, o_layer, nullptr,
                nullptr, nullptr, 1536, 3072, 768);
        else
            gemm128<64, EPI_ACC><<<dim3(12, 64), 256, 0, stream>>>(
                INTER, WoutT + (size_t)c * 1536, nullptr, nullptr, o_layer, nullptr,
                nullptr, nullptr, 1536, 3072, 768);
    }
    ln_kernel<0><<<8192, 256, 0, stream>>>(o_layer, lng, lnb, o_layer);
}

// Round 4
// 553.855 us; speedup vs baseline: 4.5242x; 1.0327x over previous
//
#include <hip/hip_runtime.h>
#include <math.h>

typedef unsigned short ushort_t;
typedef __attribute__((ext_vector_type(8))) short bf16x8;
typedef __attribute__((ext_vector_type(4))) float f32x4;

#define Dt 768
#define Mrows 8192

__device__ __forceinline__ ushort_t f2b(float f) {
    union { float f; unsigned int u; } v; v.f = f;
    unsigned int u = v.u;
    unsigned int r = (u + 0x7fffu + ((u >> 16) & 1u)) >> 16;
    return (ushort_t)r;
}
__device__ __forceinline__ float b2f(ushort_t u) {
    union { unsigned int u; float f; } v; v.u = ((unsigned int)u) << 16;
    return v.f;
}
__device__ __forceinline__ f32x4 mfma16(bf16x8 a, bf16x8 b, f32x4 c) {
    return __builtin_amdgcn_mfma_f32_16x16x32_bf16(a, b, c, 0, 0, 0);
}
__device__ __forceinline__ float gelu_exact(float v) {
    return 0.5f * v * (1.0f + erff(v * 0.70710678118654752f));
}
__device__ __forceinline__ void gl2lds16(const ushort_t* g, ushort_t* l) {
    __builtin_amdgcn_global_load_lds((const __attribute__((address_space(1))) void*)g,
                                     (__attribute__((address_space(3))) void*)l,
                                     16, 0, 0);
}

// ---------------- batched weight transpose (6x 768x768): f32 [K][N] -> bf16 [N][K] ----
__global__ __launch_bounds__(256)
void tconv6_kernel(const float* i0, const float* i1, const float* i2,
                   const float* i3, const float* i4, const float* i5,
                   ushort_t* o0, ushort_t* o1, ushort_t* o2,
                   ushort_t* o3, ushort_t* o4, ushort_t* o5)
{
    const float* in; ushort_t* out;
    switch (blockIdx.z) {
        case 0: in = i0; out = o0; break;
        case 1: in = i1; out = o1; break;
        case 2: in = i2; out = o2; break;
        case 3: in = i3; out = o3; break;
        case 4: in = i4; out = o4; break;
        default: in = i5; out = o5; break;
    }
    __shared__ float T[32][33];
    int t = threadIdx.x;
    int n0 = blockIdx.x * 32, k0 = blockIdx.y * 32;
    int r = t >> 3, c4 = (t & 7) * 4;
    float4 v = *(const float4*)(in + (size_t)(k0 + r) * 768 + n0 + c4);
    T[r][c4] = v.x; T[r][c4 + 1] = v.y; T[r][c4 + 2] = v.z; T[r][c4 + 3] = v.w;
    __syncthreads();
    int nl = t >> 3, k4 = (t & 7) * 4;
    unsigned int lo = (unsigned int)f2b(T[k4][nl]) | ((unsigned int)f2b(T[k4 + 1][nl]) << 16);
    unsigned int hi = (unsigned int)f2b(T[k4 + 2][nl]) | ((unsigned int)f2b(T[k4 + 3][nl]) << 16);
    uint2 o; o.x = lo; o.y = hi;
    *(uint2*)(out + (size_t)(n0 + nl) * 768 + k0 + k4) = o;
}

// ---------------- generic weight transpose (Wi / Wout) ----------------
__global__ __launch_bounds__(256)
void tconv_kernel(const float* __restrict__ in, ushort_t* __restrict__ out,
                  int K, int N)
{
    __shared__ float T[32][33];
    int t = threadIdx.x;
    int n0 = blockIdx.x * 32, k0 = blockIdx.y * 32;
    int r = t >> 3, c4 = (t & 7) * 4;
    float4 v = *(const float4*)(in + (size_t)(k0 + r) * N + n0 + c4);
    T[r][c4] = v.x; T[r][c4 + 1] = v.y; T[r][c4 + 2] = v.z; T[r][c4 + 3] = v.w;
    __syncthreads();
    int nl = t >> 3, k4 = (t & 7) * 4;
    unsigned int lo = (unsigned int)f2b(T[k4][nl]) | ((unsigned int)f2b(T[k4 + 1][nl]) << 16);
    unsigned int hi = (unsigned int)f2b(T[k4 + 2][nl]) | ((unsigned int)f2b(T[k4 + 3][nl]) << 16);
    uint2 o; o.x = lo; o.y = hi;
    *(uint2*)(out + (size_t)(n0 + nl) * K + k0 + k4) = o;
}

// ---------------- bias concatenation ----------------
__global__ __launch_bounds__(256)
void bconcat_kernel(const float* bq, const float* bk, const float* bv,
                    const float* gbq, const float* gbk,
                    float* bqkv, float* gbqk)
{
    int g = blockIdx.x * 256 + threadIdx.x;
    if (g < 768)       bqkv[g] = bq[g];
    else if (g < 1536) bqkv[g] = bk[g - 768];
    else if (g < 2304) bqkv[g] = bv[g - 1536];
    else if (g < 3072) gbqk[g - 2304] = gbq[g - 2304];
    else if (g < 3840) gbqk[g - 2304] = gbk[g - 3072];
}

// ---------------- fused: xb = bf16(x), hb = bf16(LN(x)) -- one x read ----------------
__global__ __launch_bounds__(256)
void lnx_kernel(const float* __restrict__ x, const float* __restrict__ g,
                const float* __restrict__ be, ushort_t* __restrict__ xb,
                ushort_t* __restrict__ hb)
{
    int row = blockIdx.x;
    const float* xr = x + (size_t)row * Dt;
    int t = threadIdx.x;
    float v0 = xr[t], v1 = xr[t + 256], v2 = xr[t + 512];
    ushort_t* xrow = xb + (size_t)row * Dt;
    xrow[t] = f2b(v0); xrow[t + 256] = f2b(v1); xrow[t + 512] = f2b(v2);
    float s = v0 + v1 + v2;
    #pragma unroll
    for (int off = 32; off; off >>= 1) s += __shfl_xor(s, off, 64);
    __shared__ float r1[4], r2[4];
    if ((t & 63) == 0) r1[t >> 6] = s;
    __syncthreads();
    float mu = (r1[0] + r1[1] + r1[2] + r1[3]) * (1.0f / Dt);
    float d0 = v0 - mu, d1 = v1 - mu, d2 = v2 - mu;
    float sq = d0 * d0 + d1 * d1 + d2 * d2;
    #pragma unroll
    for (int off = 32; off; off >>= 1) sq += __shfl_xor(sq, off, 64);
    if ((t & 63) == 0) r2[t >> 6] = sq;
    __syncthreads();
    float var = (r2[0] + r2[1] + r2[2] + r2[3]) * (1.0f / Dt);
    float rs = 1.0f / sqrtf(var + 1e-12f);
    ushort_t* hrow = hb + (size_t)row * Dt;
    hrow[t]       = f2b(d0 * rs * g[t]       + be[t]);
    hrow[t + 256] = f2b(d1 * rs * g[t + 256] + be[t + 256]);
    hrow[t + 512] = f2b(d2 * rs * g[t + 512] + be[t + 512]);
}

// ---------------- final LayerNorm (f32 in/out) ----------------
__global__ __launch_bounds__(256)
void ln_kernel(const float* __restrict__ x, const float* __restrict__ g,
               const float* __restrict__ be, float* __restrict__ out)
{
    int row = blockIdx.x;
    const float* xr = x + (size_t)row * Dt;
    int t = threadIdx.x;
    float v0 = xr[t], v1 = xr[t + 256], v2 = xr[t + 512];
    float s = v0 + v1 + v2;
    #pragma unroll
    for (int off = 32; off; off >>= 1) s += __shfl_xor(s, off, 64);
    __shared__ float r1[4], r2[4];
    if ((t & 63) == 0) r1[t >> 6] = s;
    __syncthreads();
    float mu = (r1[0] + r1[1] + r1[2] + r1[3]) * (1.0f / Dt);
    float d0 = v0 - mu, d1 = v1 - mu, d2 = v2 - mu;
    float sq = d0 * d0 + d1 * d1 + d2 * d2;
    #pragma unroll
    for (int off = 32; off; off >>= 1) sq += __shfl_xor(sq, off, 64);
    if ((t & 63) == 0) r2[t >> 6] = sq;
    __syncthreads();
    float var = (r2[0] + r2[1] + r2[2] + r2[3]) * (1.0f / Dt);
    float rs = 1.0f / sqrtf(var + 1e-12f);
    float* orow = out + (size_t)row * Dt;
    orow[t]       = d0 * rs * g[t]       + be[t];
    orow[t + 256] = d1 * rs * g[t + 256] + be[t + 256];
    orow[t + 512] = d2 * rs * g[t + 512] + be[t + 512];
}

// ---------------- bf16 MFMA GEMM, m97 structure: global_load_lds(16B) ----------------
enum { EPI_BF16 = 1, EPI_QKV = 2, EPI_DUAL = 3, EPI_GELU = 4, EPI_RES = 5, EPI_ACC = 6 };

template<int BN, int EPI>
__global__ __launch_bounds__(256)
void gemm128(const ushort_t* __restrict__ A, const ushort_t* __restrict__ Bt,
             const float* __restrict__ bias, const float* __restrict__ res,
             float* __restrict__ Cf, ushort_t* __restrict__ O0,
             ushort_t* __restrict__ O1, ushort_t* __restrict__ O2,
             int K, int ldb, int ldc)
{
    constexpr int NF = BN / 32;
    __shared__ ushort_t As[128 * 32];
    __shared__ ushort_t Bs[BN * 32];
    int t = threadIdx.x;
    int w = t >> 6, l = t & 63;
    int wr = w >> 1, wc = w & 1;
    int lr = l & 15, lg = l >> 4;
    int bn = blockIdx.x * BN;
    int bm = blockIdx.y * 128;

    const ushort_t* gA0 = A + (size_t)(bm + (t >> 2)) * K + ((t & 3) << 3);
    const ushort_t* gA1 = A + (size_t)(bm + 64 + (t >> 2)) * K + ((t & 3) << 3);
    const ushort_t* gB0 = Bt + (size_t)(bn + (t >> 2)) * ldb + ((t & 3) << 3);
    const ushort_t* gB1 = (BN == 128) ?
        Bt + (size_t)(bn + 64 + (t >> 2)) * ldb + ((t & 3) << 3) : nullptr;
    ushort_t* lA0 = As + (w << 9);
    ushort_t* lA1 = As + 2048 + (w << 9);
    ushort_t* lB0 = Bs + (w << 9);
    ushort_t* lB1 = Bs + 2048 + (w << 9);

    f32x4 acc[4][NF];
    #pragma unroll
    for (int m = 0; m < 4; ++m)
        #pragma unroll
        for (int n = 0; n < NF; ++n) acc[m][n] = (f32x4)0.0f;

    for (int k0 = 0; k0 < K; k0 += 32) {
        gl2lds16(gA0 + k0, lA0);
        gl2lds16(gA1 + k0, lA1);
        gl2lds16(gB0 + k0, lB0);
        if (BN == 128) gl2lds16(gB1 + k0, lB1);
        __syncthreads();
        bf16x8 af[4], bfv[NF];
        #pragma unroll
        for (int m = 0; m < 4; ++m)
            af[m] = *(const bf16x8*)&As[(wr * 64 + m * 16 + lr) * 32 + lg * 8];
        #pragma unroll
        for (int n = 0; n < NF; ++n)
            bfv[n] = *(const bf16x8*)&Bs[(wc * (BN / 2) + n * 16 + lr) * 32 + lg * 8];
        __builtin_amdgcn_s_setprio(1);
        #pragma unroll
        for (int m = 0; m < 4; ++m)
            #pragma unroll
            for (int n = 0; n < NF; ++n)
                acc[m][n] = mfma16(af[m], bfv[n], acc[m][n]);
        __builtin_amdgcn_s_setprio(0);
        __syncthreads();
    }

    #pragma unroll
    for (int m = 0; m < 4; ++m) {
        int row0 = bm + wr * 64 + m * 16 + lg * 4;
        #pragma unroll
        for (int n = 0; n < NF; ++n) {
            int ng = bn + wc * (BN / 2) + n * 16 + lr;
            float v0 = acc[m][n][0], v1 = acc[m][n][1];
            float v2 = acc[m][n][2], v3 = acc[m][n][3];
            if (EPI != EPI_ACC) {
                float bv = bias[ng];
                v0 += bv; v1 += bv; v2 += bv; v3 += bv;
            }
            if (EPI == EPI_BF16) {
                O0[(size_t)(row0 + 0) * ldc + ng] = f2b(v0);
                O0[(size_t)(row0 + 1) * ldc + ng] = f2b(v1);
                O0[(size_t)(row0 + 2) * ldc + ng] = f2b(v2);
                O0[(size_t)(row0 + 3) * ldc + ng] = f2b(v3);
            } else if (EPI == EPI_QKV) {
                if (bn < 768) {
                    O0[(size_t)(row0 + 0) * 768 + ng] = f2b(v0 * 0.125f);
                    O0[(size_t)(row0 + 1) * 768 + ng] = f2b(v1 * 0.125f);
                    O0[(size_t)(row0 + 2) * 768 + ng] = f2b(v2 * 0.125f);
                    O0[(size_t)(row0 + 3) * 768 + ng] = f2b(v3 * 0.125f);
                } else if (bn < 1536) {
                    int c = ng - 768;
                    O1[(size_t)(row0 + 0) * 768 + c] = f2b(v0);
                    O1[(size_t)(row0 + 1) * 768 + c] = f2b(v1);
                    O1[(size_t)(row0 + 2) * 768 + c] = f2b(v2);
                    O1[(size_t)(row0 + 3) * 768 + c] = f2b(v3);
                } else {
                    int dk = ng - 1536;
                    unsigned int lo = (unsigned int)f2b(v0) | ((unsigned int)f2b(v1) << 16);
                    unsigned int hi = (unsigned int)f2b(v2) | ((unsigned int)f2b(v3) << 16);
                    uint2 o; o.x = lo; o.y = hi;
                    *(uint2*)(O2 + (size_t)dk * Mrows + row0) = o;
                }
            } else if (EPI == EPI_DUAL) {
                Cf[(size_t)(row0 + 0) * ldc + ng] = v0;
                Cf[(size_t)(row0 + 1) * ldc + ng] = v1;
                Cf[(size_t)(row0 + 2) * ldc + ng] = v2;
                Cf[(size_t)(row0 + 3) * ldc + ng] = v3;
                O0[(size_t)(row0 + 0) * ldc + ng] = f2b(v0);
                O0[(size_t)(row0 + 1) * ldc + ng] = f2b(v1);
                O0[(size_t)(row0 + 2) * ldc + ng] = f2b(v2);
                O0[(size_t)(row0 + 3) * ldc + ng] = f2b(v3);
            } else if (EPI == EPI_GELU) {
                O0[(size_t)(row0 + 0) * ldc + ng] = f2b(gelu_exact(v0));
                O0[(size_t)(row0 + 1) * ldc + ng] = f2b(gelu_exact(v1));
                O0[(size_t)(row0 + 2) * ldc + ng] = f2b(gelu_exact(v2));
                O0[(size_t)(row0 + 3) * ldc + ng] = f2b(gelu_exact(v3));
            } else if (EPI == EPI_RES) {
                Cf[(size_t)(row0 + 0) * ldc + ng] = v0 + res[(size_t)(row0 + 0) * Dt + ng];
                Cf[(size_t)(row0 + 1) * ldc + ng] = v1 + res[(size_t)(row0 + 1) * Dt + ng];
                Cf[(size_t)(row0 + 2) * ldc + ng] = v2 + res[(size_t)(row0 + 2) * Dt + ng];
                Cf[(size_t)(row0 + 3) * ldc + ng] = v3 + res[(size_t)(row0 + 3) * Dt + ng];
            } else if (EPI == EPI_ACC) {
                Cf[(size_t)(row0 + 0) * ldc + ng] += v0;
                Cf[(size_t)(row0 + 1) * ldc + ng] += v1;
                Cf[(size_t)(row0 + 2) * ldc + ng] += v2;
                Cf[(size_t)(row0 + 3) * ldc + ng] += v3;
            }
        }
    }
}

// ---------------- group attention ----------------
__global__ __launch_bounds__(256)
void group_scores_kernel(const ushort_t* __restrict__ GQK, const int* __restrict__ am,
                         float* __restrict__ smU, float* __restrict__ smD,
                         int* __restrict__ emptyF)
{
    int gi = blockIdx.x;
    int b = gi >> 9, s = gi & 511;
    int t = threadIdx.x;
    const ushort_t* qr = GQK + (size_t)gi * 1536;
    bool hasU = (s < 511) && (am[(b << 9) + s + 1] != 0);
    bool hasD = (s > 0)   && (am[(b << 9) + s - 1] != 0);
    float su = 0.0f, sd = 0.0f;
    if (hasU) {
        const ushort_t* kr = GQK + (size_t)(gi + 1) * 1536 + 768;
        for (int c = t; c < Dt; c += 256) su += b2f(qr[c]) * b2f(kr[c]);
    }
    if (hasD) {
        const ushort_t* kr = GQK + (size_t)(gi - 1) * 1536 + 768;
        for (int c = t; c < Dt; c += 256) sd += b2f(qr[c]) * b2f(kr[c]);
    }
    #pragma unroll
    for (int off = 32; off; off >>= 1) { su += __shfl_xor(su, off, 64); sd += __shfl_xor(sd, off, 64); }
    __shared__ float rU[4], rD[4];
    if ((t & 63) == 0) { rU[t >> 6] = su; rD[t >> 6] = sd; }
    __syncthreads();
    if (t == 0) {
        su = (rU[0] + rU[1] + rU[2] + rU[3]) * (1.0f / Dt);
        sd = (rD[0] + rD[1] + rD[2] + rD[3]) * (1.0f / Dt);
        float u, d2; int emp = 0;
        if (hasU && hasD) {
            float m = fmaxf(su, sd);
            float eu = __expf(su - m), ed = __expf(sd - m);
            float inv = 1.0f / (eu + ed);
            u = eu * inv; d2 = ed * inv;
        } else if (hasU) { u = 1.0f; d2 = 0.0f; }
        else if (hasD)   { u = 0.0f; d2 = 1.0f; }
        else { u = d2 = 1.0f / 512.0f; emp = 1; }
        smU[gi] = u; smD[gi] = d2; emptyF[gi] = emp;
    }
}

// per-batch prefix of log(neigh superdiag); computes superdiag from smU/smD/prior
__global__ __launch_bounds__(64)
void prefix_kernel(const float* __restrict__ prior, const float* __restrict__ smU,
                   const float* __restrict__ smD, float* __restrict__ P)
{
    int b = blockIdx.x;
    int l = threadIdx.x;
    float lv[8];
    float run = 0.0f;
    #pragma unroll
    for (int e = 0; e < 8; ++e) {
        int j = l * 8 + e;
        float lj = 0.0f;
        if (j < 511) {
            float pr = prior[((size_t)((b << 9) + j)) * 512 + j + 1];
            float nv = pr + (1.0f - pr) *
                       sqrtf(smU[(b << 9) + j] * smD[(b << 9) + j + 1] + 1e-9f);
            lj = logf(nv + 1e-9f);
        }
        lv[e] = run;
        run += lj;
    }
    float tot = run;
    float scan = tot;
    #pragma unroll
    for (int off = 1; off < 64; off <<= 1) {
        float n = __shfl_up(scan, off, 64);
        if (l >= off) scan += n;
    }
    float excl = scan - tot;
    #pragma unroll
    for (int e = 0; e < 8; ++e)
        P[b * 512 + l * 8 + e] = excl + lv[e];
}

// fused: neigh output + C output (f32 + bf16 scratch copy)
__global__ __launch_bounds__(512)
void neigh_cfill_kernel(const float* __restrict__ prior,
                        const float* __restrict__ smU, const float* __restrict__ smD,
                        const int* __restrict__ emptyF, const float* __restrict__ P,
                        float* __restrict__ ne_out, float* __restrict__ C_out,
                        ushort_t* __restrict__ CB)
{
    int bi = blockIdx.x;
    int j  = threadIdx.x;
    int b = bi >> 9, i = bi & 511;
    int bj = (b << 9) + j;
    const float invS = 1.0f / 512.0f;
    float fij, fji;
    if (j == i + 1)      { fij = smU[bi]; fji = smD[bj]; }
    else if (j == i - 1) { fij = smD[bi]; fji = smU[bj]; }
    else { fij = emptyF[bi] ? invS : 0.0f; fji = emptyF[bj] ? invS : 0.0f; }
    float val = sqrtf(fij * fji + 1e-9f);
    float pr = prior[(size_t)bi * 512 + j];
    float nv = pr + (1.0f - pr) * val;
    ne_out[(size_t)bi * 512 + j] = nv;
    float pi = P[bi], pj = P[bj];
    float v;
    if (j > i)      v = expf(pj - pi) + 1e-9f;
    else if (j < i) v = expf(pi - pj) + 1e-9f;
    else            v = nv;
    C_out[(size_t)bi * 512 + j] = v;
    CB[(size_t)bi * 512 + j] = f2b(v);
}

// ---------------- MFMA flash MHA, static-max softmax, bf16 C ----------------
#define SMAX 12.0f
__global__ __launch_bounds__(256)
void mha_mfma(const ushort_t* __restrict__ q, const ushort_t* __restrict__ k,
              const ushort_t* __restrict__ vt, const int* __restrict__ am,
              const ushort_t* __restrict__ CB, ushort_t* __restrict__ ctx)
{
    __shared__ ushort_t Qs[64][72];
    __shared__ ushort_t Ks[64][72];
    __shared__ ushort_t Vs[64][72];   // [dk][key]
    __shared__ ushort_t Ps[64][72];
    int t = threadIdx.x;
    int w = t >> 6, l = t & 63;
    int lr = l & 15, lg = l >> 4;
    int kb8 = lg << 3;
    int qt = blockIdx.x, h = blockIdx.y, b = blockIdx.z;
    int hoff = h * 64;
    int q0 = qt * 64;
    int q0g = (b << 9) + q0;
    int myrow = w * 16 + lg * 4;

    #pragma unroll
    for (int i = 0; i < 2; ++i) {
        int c = t + i * 256;
        int r = c >> 3, dc = (c & 7) << 3;
        *(uint4*)&Qs[r][dc] = *(const uint4*)(q + (size_t)(q0g + r) * Dt + hoff + dc);
    }

    f32x4 oacc[4];
    #pragma unroll
    for (int n = 0; n < 4; ++n) oacc[n] = (f32x4)0.0f;
    float l_run[4] = {0.0f, 0.0f, 0.0f, 0.0f};

    for (int kb = 0; kb < 8; ++kb) {
        __syncthreads();
        #pragma unroll
        for (int i = 0; i < 2; ++i) {
            int c = t + i * 256;
            int r = c >> 3, dc = (c & 7) << 3;
            *(uint4*)&Ks[r][dc] =
                *(const uint4*)(k + (size_t)((b << 9) + kb * 64 + r) * Dt + hoff + dc);
            *(uint4*)&Vs[r][dc] =
                *(const uint4*)(vt + (size_t)(hoff + r) * Mrows + (b << 9) + kb * 64 + dc);
        }
        __syncthreads();

        // early loads (overlap with QK^T)
        int amv[4];
        #pragma unroll
        for (int n = 0; n < 4; ++n) amv[n] = am[(b << 9) + kb * 64 + n * 16 + lr];
        float cc[4][4];
        #pragma unroll
        for (int n = 0; n < 4; ++n)
            #pragma unroll
            for (int r = 0; r < 4; ++r)
                cc[n][r] = b2f(CB[(size_t)(q0g + myrow + r) * 512 + kb * 64 + n * 16 + lr]);

        f32x4 s[4];
        #pragma unroll
        for (int n = 0; n < 4; ++n) s[n] = (f32x4)0.0f;
        __builtin_amdgcn_s_setprio(1);
        #pragma unroll
        for (int ks = 0; ks < 2; ++ks) {
            bf16x8 aq = *(const bf16x8*)&Qs[w * 16 + lr][ks * 32 + kb8];
            #pragma unroll
            for (int n = 0; n < 4; ++n) {
                bf16x8 bk = *(const bf16x8*)&Ks[n * 16 + lr][ks * 32 + kb8];
                s[n] = mfma16(aq, bk, s[n]);
            }
        }
        __builtin_amdgcn_s_setprio(0);

        // static-max softmax: p = exp(s - SMAX), masked -> 0 (identical ratios)
        float pf[4][4];
        #pragma unroll
        for (int n = 0; n < 4; ++n) {
            int key = kb * 64 + n * 16 + lr;
            #pragma unroll
            for (int r = 0; r < 4; ++r) {
                int qrow = q0 + myrow + r;
                bool ok = (amv[n] != 0) || (key == qrow);
                float p = ok ? __expf(s[n][r] - SMAX) : 0.0f;
                pf[n][r] = p;
                l_run[r] += p;
            }
        }
        #pragma unroll
        for (int n = 0; n < 4; ++n)
            #pragma unroll
            for (int r = 0; r < 4; ++r)
                Ps[myrow + r][n * 16 + lr] = f2b(pf[n][r] * cc[n][r]);

        __builtin_amdgcn_s_setprio(1);
        #pragma unroll
        for (int ks = 0; ks < 2; ++ks) {
            bf16x8 ap = *(const bf16x8*)&Ps[w * 16 + lr][ks * 32 + kb8];
            #pragma unroll
            for (int n = 0; n < 4; ++n) {
                bf16x8 bv = *(const bf16x8*)&Vs[n * 16 + lr][ks * 32 + kb8];
                oacc[n] = mfma16(ap, bv, oacc[n]);
            }
        }
        __builtin_amdgcn_s_setprio(0);
    }
    // one final reduce of l across the 16 lanes of this lg-group
    #pragma unroll
    for (int r = 0; r < 4; ++r) {
        #pragma unroll
        for (int off = 1; off < 16; off <<= 1)
            l_run[r] += __shfl_xor(l_run[r], off, 64);
    }
    #pragma unroll
    for (int r = 0; r < 4; ++r) {
        float inv = 1.0f / l_run[r];
        #pragma unroll
        for (int n = 0; n < 4; ++n)
            ctx[(size_t)(q0g + myrow + r) * Dt + hoff + n * 16 + lr] =
                f2b(oacc[n][r] * inv);
    }
}

// -----------------------------------------------------------------------------------
extern "C" void kernel_launch(void* const* d_in, const int* in_sizes, int n_in,
                              void* d_out, int out_size, void* d_ws, size_t ws_size,
                              hipStream_t stream)
{
    (void)in_sizes; (void)n_in; (void)out_size; (void)ws_size;
    const float* x     = (const float*)d_in[0];
    const float* prior = (const float*)d_in[1];
    const int*   am    = (const int*)  d_in[2];
    const float* Wq = (const float*)d_in[3];   const float* bq = (const float*)d_in[4];
    const float* Wk = (const float*)d_in[5];   const float* bk = (const float*)d_in[6];
    const float* Wv = (const float*)d_in[7];   const float* bv = (const float*)d_in[8];
    const float* Wo = (const float*)d_in[9];   const float* bo = (const float*)d_in[10];
    const float* gWk = (const float*)d_in[11]; const float* gbk = (const float*)d_in[12];
    const float* gWq = (const float*)d_in[13]; const float* gbq = (const float*)d_in[14];
    const float* glng = (const float*)d_in[15]; const float* glnb = (const float*)d_in[16];
    const float* Wi = (const float*)d_in[17];  const float* bi = (const float*)d_in[18];
    const float* Wout = (const float*)d_in[19]; const float* bout = (const float*)d_in[20];
    const float* lng = (const float*)d_in[21]; const float* lnb = (const float*)d_in[22];

    float* out = (float*)d_out;
    float* o_layer = out;
    float* o_C     = out + (size_t)6291456;
    float* o_neigh = out + (size_t)10485760;
    float* o_attn  = out + (size_t)14680064;
    // bf16 C scratch lives in the (not-yet-written) o_attn region; Wo GEMM
    // overwrites it after mha consumes it.
    ushort_t* CB = (ushort_t*)o_attn;

    // ---- workspace layout ----
    char* base = (char*)d_ws;
    ushort_t* WqkvT = (ushort_t*)(base);                  // [2304][768]
    ushort_t* gWqkT = (ushort_t*)(base + 3538944);        // [1536][768]
    ushort_t* WoT   = (ushort_t*)(base + 5898240);        // [768][768]
    ushort_t* WiT   = (ushort_t*)(base + 7077888);        // [3072][768]
    ushort_t* WoutT = (ushort_t*)(base + 11796480);       // [768][3072]
    float*    bqkv  = (float*)(base + 16515072);
    float*    gbqk  = (float*)(base + 16524288);
    float*    smU   = (float*)(base + 16530432);
    float*    smD   = (float*)(base + 16563200);
    float*    Ppre  = (float*)(base + 16595968);
    int*      emptyF= (int*)(base + 16628736);
    ushort_t* s0 = (ushort_t*)(base + 16661504);          // 12.6 MB: XB / CTXB
    ushort_t* s1 = (ushort_t*)(base + 29244416);          // 12.6 MB: HB / QB / AB16
    ushort_t* s2 = (ushort_t*)(base + 41827328);          // 25.2 MB: GQK / KB+VT / INTER
    ushort_t* XB = s0;    ushort_t* CTXB = s0;
    ushort_t* HB = s1;    ushort_t* QB = s1;   ushort_t* AB16 = s1;
    ushort_t* GQK = s2;   ushort_t* KB = s2;   ushort_t* INTER = s2;
    ushort_t* VT = s2 + 6291456;                          // [768][8192]

    // ---- weight prep ----
    tconv6_kernel<<<dim3(24, 24, 6), 256, 0, stream>>>(
        Wq, Wk, Wv, gWq, gWk, Wo,
        WqkvT, WqkvT + 589824, WqkvT + 1179648, gWqkT, gWqkT + 589824, WoT);
    tconv_kernel<<<dim3(96, 24), 256, 0, stream>>>(Wi, WiT, 768, 3072);
    tconv_kernel<<<dim3(24, 96), 256, 0, stream>>>(Wout, WoutT, 3072, 768);
    bconcat_kernel<<<15, 256, 0, stream>>>(bq, bk, bv, gbq, gbk, bqkv, gbqk);

    // ---- group attention ----
    lnx_kernel<<<8192, 256, 0, stream>>>(x, glng, glnb, XB, HB);
    gemm128<128, EPI_BF16><<<dim3(12, 64), 256, 0, stream>>>(
        HB, gWqkT, gbqk, nullptr, nullptr, GQK, nullptr, nullptr, 768, 768, 1536);
    group_scores_kernel<<<8192, 256, 0, stream>>>(GQK, am, smU, smD, emptyF);
    prefix_kernel<<<16, 64, 0, stream>>>(prior, smU, smD, Ppre);
    neigh_cfill_kernel<<<8192, 512, 0, stream>>>(prior, smU, smD, emptyF, Ppre,
                                                 o_neigh, o_C, CB);

    // ---- multi-head attention ----
    gemm128<128, EPI_QKV><<<dim3(18, 64), 256, 0, stream>>>(
        XB, WqkvT, bqkv, nullptr, nullptr, QB, KB, VT, 768, 768, 768);
    mha_mfma<<<dim3(8, 12, 16), 256, 0, stream>>>(QB, KB, VT, am, CB, CTXB);
    gemm128<64, EPI_DUAL><<<dim3(12, 64), 256, 0, stream>>>(
        CTXB, WoT, bo, nullptr, o_attn, AB16, nullptr, nullptr, 768, 768, 768);

    // ---- FFN, 2 chunks of 1536 over DI ----
    for (int c = 0; c < 2; ++c) {
        gemm128<128, EPI_GELU><<<dim3(12, 64), 256, 0, stream>>>(
            AB16, WiT + (size_t)c * 1536 * 768, bi + (size_t)c * 1536, nullptr,
            nullptr, INTER, nullptr, nullptr, 768, 768, 1536);
        if (c == 0)
            gemm128<64, EPI_RES><<<dim3(12, 64), 256, 0, stream>>>(
                INTER, WoutT + (size_t)c * 1536, bout, o_attn, o_layer, nullptr,
                nullptr, nullptr, 1536, 3072, 768);
        else
            gemm128<64, EPI_ACC><<<dim3(12, 64), 256, 0, stream>>>(
                INTER, WoutT + (size_t)c * 1536, nullptr, nullptr, o_layer, nullptr,
                nullptr, nullptr, 1536, 3072, 768);
    }
    ln_kernel<<<8192, 256, 0, stream>>>(o_layer, lng, lnb, o_layer);
}

// Round 5
// 523.415 us; speedup vs baseline: 4.7873x; 1.0582x over previous
//
#include <hip/hip_runtime.h>
#include <math.h>

typedef unsigned short ushort_t;
typedef __attribute__((ext_vector_type(8))) short bf16x8;
typedef __attribute__((ext_vector_type(4))) float f32x4;

#define Dt 768
#define Mrows 8192

__device__ __forceinline__ ushort_t f2b(float f) {
    union { float f; unsigned int u; } v; v.f = f;
    unsigned int u = v.u;
    unsigned int r = (u + 0x7fffu + ((u >> 16) & 1u)) >> 16;
    return (ushort_t)r;
}
__device__ __forceinline__ float b2f(ushort_t u) {
    union { unsigned int u; float f; } v; v.u = ((unsigned int)u) << 16;
    return v.f;
}
__device__ __forceinline__ f32x4 mfma16(bf16x8 a, bf16x8 b, f32x4 c) {
    return __builtin_amdgcn_mfma_f32_16x16x32_bf16(a, b, c, 0, 0, 0);
}
__device__ __forceinline__ float gelu_exact(float v) {
    return 0.5f * v * (1.0f + erff(v * 0.70710678118654752f));
}
__device__ __forceinline__ void gl2lds16(const ushort_t* g, ushort_t* l) {
    __builtin_amdgcn_global_load_lds((const __attribute__((address_space(1))) void*)g,
                                     (__attribute__((address_space(3))) void*)l,
                                     16, 0, 0);
}

// ---------------- batched weight transpose (6x 768x768): f32 [K][N] -> bf16 [N][K] ----
__global__ __launch_bounds__(256)
void tconv6_kernel(const float* i0, const float* i1, const float* i2,
                   const float* i3, const float* i4, const float* i5,
                   ushort_t* o0, ushort_t* o1, ushort_t* o2,
                   ushort_t* o3, ushort_t* o4, ushort_t* o5)
{
    const float* in; ushort_t* out;
    switch (blockIdx.z) {
        case 0: in = i0; out = o0; break;
        case 1: in = i1; out = o1; break;
        case 2: in = i2; out = o2; break;
        case 3: in = i3; out = o3; break;
        case 4: in = i4; out = o4; break;
        default: in = i5; out = o5; break;
    }
    __shared__ float T[32][33];
    int t = threadIdx.x;
    int n0 = blockIdx.x * 32, k0 = blockIdx.y * 32;
    int r = t >> 3, c4 = (t & 7) * 4;
    float4 v = *(const float4*)(in + (size_t)(k0 + r) * 768 + n0 + c4);
    T[r][c4] = v.x; T[r][c4 + 1] = v.y; T[r][c4 + 2] = v.z; T[r][c4 + 3] = v.w;
    __syncthreads();
    int nl = t >> 3, k4 = (t & 7) * 4;
    unsigned int lo = (unsigned int)f2b(T[k4][nl]) | ((unsigned int)f2b(T[k4 + 1][nl]) << 16);
    unsigned int hi = (unsigned int)f2b(T[k4 + 2][nl]) | ((unsigned int)f2b(T[k4 + 3][nl]) << 16);
    uint2 o; o.x = lo; o.y = hi;
    *(uint2*)(out + (size_t)(n0 + nl) * 768 + k0 + k4) = o;
}

// ---------------- generic weight transpose (Wi / Wout) ----------------
__global__ __launch_bounds__(256)
void tconv_kernel(const float* __restrict__ in, ushort_t* __restrict__ out,
                  int K, int N)
{
    __shared__ float T[32][33];
    int t = threadIdx.x;
    int n0 = blockIdx.x * 32, k0 = blockIdx.y * 32;
    int r = t >> 3, c4 = (t & 7) * 4;
    float4 v = *(const float4*)(in + (size_t)(k0 + r) * N + n0 + c4);
    T[r][c4] = v.x; T[r][c4 + 1] = v.y; T[r][c4 + 2] = v.z; T[r][c4 + 3] = v.w;
    __syncthreads();
    int nl = t >> 3, k4 = (t & 7) * 4;
    unsigned int lo = (unsigned int)f2b(T[k4][nl]) | ((unsigned int)f2b(T[k4 + 1][nl]) << 16);
    unsigned int hi = (unsigned int)f2b(T[k4 + 2][nl]) | ((unsigned int)f2b(T[k4 + 3][nl]) << 16);
    uint2 o; o.x = lo; o.y = hi;
    *(uint2*)(out + (size_t)(n0 + nl) * K + k0 + k4) = o;
}

// ---------------- bias concatenation ----------------
__global__ __launch_bounds__(256)
void bconcat_kernel(const float* bq, const float* bk, const float* bv,
                    const float* gbq, const float* gbk,
                    float* bqkv, float* gbqk)
{
    int g = blockIdx.x * 256 + threadIdx.x;
    if (g < 768)       bqkv[g] = bq[g];
    else if (g < 1536) bqkv[g] = bk[g - 768];
    else if (g < 2304) bqkv[g] = bv[g - 1536];
    else if (g < 3072) gbqk[g - 2304] = gbq[g - 2304];
    else if (g < 3840) gbqk[g - 2304] = gbk[g - 3072];
}

// ---------------- fused: xb = bf16(x), hb = bf16(LN(x)) ----------------
__global__ __launch_bounds__(256)
void lnx_kernel(const float* __restrict__ x, const float* __restrict__ g,
                const float* __restrict__ be, ushort_t* __restrict__ xb,
                ushort_t* __restrict__ hb)
{
    int row = blockIdx.x;
    const float* xr = x + (size_t)row * Dt;
    int t = threadIdx.x;
    float v0 = xr[t], v1 = xr[t + 256], v2 = xr[t + 512];
    ushort_t* xrow = xb + (size_t)row * Dt;
    xrow[t] = f2b(v0); xrow[t + 256] = f2b(v1); xrow[t + 512] = f2b(v2);
    float s = v0 + v1 + v2;
    #pragma unroll
    for (int off = 32; off; off >>= 1) s += __shfl_xor(s, off, 64);
    __shared__ float r1[4], r2[4];
    if ((t & 63) == 0) r1[t >> 6] = s;
    __syncthreads();
    float mu = (r1[0] + r1[1] + r1[2] + r1[3]) * (1.0f / Dt);
    float d0 = v0 - mu, d1 = v1 - mu, d2 = v2 - mu;
    float sq = d0 * d0 + d1 * d1 + d2 * d2;
    #pragma unroll
    for (int off = 32; off; off >>= 1) sq += __shfl_xor(sq, off, 64);
    if ((t & 63) == 0) r2[t >> 6] = sq;
    __syncthreads();
    float var = (r2[0] + r2[1] + r2[2] + r2[3]) * (1.0f / Dt);
    float rs = 1.0f / sqrtf(var + 1e-12f);
    ushort_t* hrow = hb + (size_t)row * Dt;
    hrow[t]       = f2b(d0 * rs * g[t]       + be[t]);
    hrow[t + 256] = f2b(d1 * rs * g[t + 256] + be[t + 256]);
    hrow[t + 512] = f2b(d2 * rs * g[t + 512] + be[t + 512]);
}

// ---------------- final LayerNorm (f32 in/out) ----------------
__global__ __launch_bounds__(256)
void ln_kernel(const float* __restrict__ x, const float* __restrict__ g,
               const float* __restrict__ be, float* __restrict__ out)
{
    int row = blockIdx.x;
    const float* xr = x + (size_t)row * Dt;
    int t = threadIdx.x;
    float v0 = xr[t], v1 = xr[t + 256], v2 = xr[t + 512];
    float s = v0 + v1 + v2;
    #pragma unroll
    for (int off = 32; off; off >>= 1) s += __shfl_xor(s, off, 64);
    __shared__ float r1[4], r2[4];
    if ((t & 63) == 0) r1[t >> 6] = s;
    __syncthreads();
    float mu = (r1[0] + r1[1] + r1[2] + r1[3]) * (1.0f / Dt);
    float d0 = v0 - mu, d1 = v1 - mu, d2 = v2 - mu;
    float sq = d0 * d0 + d1 * d1 + d2 * d2;
    #pragma unroll
    for (int off = 32; off; off >>= 1) sq += __shfl_xor(sq, off, 64);
    if ((t & 63) == 0) r2[t >> 6] = sq;
    __syncthreads();
    float var = (r2[0] + r2[1] + r2[2] + r2[3]) * (1.0f / Dt);
    float rs = 1.0f / sqrtf(var + 1e-12f);
    float* orow = out + (size_t)row * Dt;
    orow[t]       = d0 * rs * g[t]       + be[t];
    orow[t + 256] = d1 * rs * g[t + 256] + be[t + 256];
    orow[t + 512] = d2 * rs * g[t + 512] + be[t + 512];
}

// ---------------- bf16 MFMA GEMM: dbuf 2-phase prefetch + XCD swizzle ----------------
enum { EPI_BF16 = 1, EPI_QKV = 2, EPI_DUAL = 3, EPI_GELU = 4, EPI_RES = 5, EPI_ACC = 6 };

template<int BN, int EPI>
__global__ __launch_bounds__(256)
void gemm128(const ushort_t* __restrict__ A, const ushort_t* __restrict__ Bt,
             const float* __restrict__ bias, const float* __restrict__ res,
             float* __restrict__ Cf, ushort_t* __restrict__ O0,
             ushort_t* __restrict__ O1, ushort_t* __restrict__ O2,
             int K, int ldb, int ldc)
{
    constexpr int NF = BN / 32;
    constexpr int AHALF = 128 * 32;          // ushorts per buffer half
    constexpr int BHALF = BN * 32;
    __shared__ ushort_t As[2 * AHALF];
    __shared__ ushort_t Bs[2 * BHALF];
    int t = threadIdx.x;
    int w = t >> 6, l = t & 63;
    int wr = w >> 1, wc = w & 1;
    int lr = l & 15, lg = l >> 4;

    // XCD-aware chunked swizzle (grids are multiples of 8)
    int nwg = gridDim.x * gridDim.y;
    int bid = blockIdx.y * gridDim.x + blockIdx.x;
    int per = nwg >> 3;
    int sw  = (bid & 7) * per + (bid >> 3);
    int bn = (sw % gridDim.x) * BN;
    int bm = (sw / gridDim.x) * 128;

    const ushort_t* gA0 = A + (size_t)(bm + (t >> 2)) * K + ((t & 3) << 3);
    const ushort_t* gA1 = A + (size_t)(bm + 64 + (t >> 2)) * K + ((t & 3) << 3);
    const ushort_t* gB0 = Bt + (size_t)(bn + (t >> 2)) * ldb + ((t & 3) << 3);
    const ushort_t* gB1 = (BN == 128) ?
        Bt + (size_t)(bn + 64 + (t >> 2)) * ldb + ((t & 3) << 3) : nullptr;
    int woff = (w << 9);

    f32x4 acc[4][NF];
    #pragma unroll
    for (int m = 0; m < 4; ++m)
        #pragma unroll
        for (int n = 0; n < NF; ++n) acc[m][n] = (f32x4)0.0f;

    // prologue: stage tile 0 into buffer 0
    gl2lds16(gA0, As + woff);
    gl2lds16(gA1, As + 2048 + woff);
    gl2lds16(gB0, Bs + woff);
    if (BN == 128) gl2lds16(gB1, Bs + 2048 + woff);
    __syncthreads();

    int cur = 0;
    for (int k0 = 0; k0 < K; k0 += 32) {
        // phase 1: issue next tile's loads into the other buffer
        if (k0 + 32 < K) {
            int nb = (cur ^ 1);
            gl2lds16(gA0 + k0 + 32, As + nb * AHALF + woff);
            gl2lds16(gA1 + k0 + 32, As + nb * AHALF + 2048 + woff);
            gl2lds16(gB0 + k0 + 32, Bs + nb * BHALF + woff);
            if (BN == 128) gl2lds16(gB1 + k0 + 32, Bs + nb * BHALF + 2048 + woff);
        }
        // phase 2: compute on current buffer (loads in flight above)
        const ushort_t* Ab = As + cur * AHALF;
        const ushort_t* Bb = Bs + cur * BHALF;
        bf16x8 af[4], bfv[NF];
        #pragma unroll
        for (int m = 0; m < 4; ++m)
            af[m] = *(const bf16x8*)&Ab[(wr * 64 + m * 16 + lr) * 32 + lg * 8];
        #pragma unroll
        for (int n = 0; n < NF; ++n)
            bfv[n] = *(const bf16x8*)&Bb[(wc * (BN / 2) + n * 16 + lr) * 32 + lg * 8];
        __builtin_amdgcn_s_setprio(1);
        #pragma unroll
        for (int m = 0; m < 4; ++m)
            #pragma unroll
            for (int n = 0; n < NF; ++n)
                acc[m][n] = mfma16(af[m], bfv[n], acc[m][n]);
        __builtin_amdgcn_s_setprio(0);
        __syncthreads();     // drains staged loads (vmcnt) + flip barrier
        cur ^= 1;
    }

    #pragma unroll
    for (int m = 0; m < 4; ++m) {
        int row0 = bm + wr * 64 + m * 16 + lg * 4;
        #pragma unroll
        for (int n = 0; n < NF; ++n) {
            int ng = bn + wc * (BN / 2) + n * 16 + lr;
            float v0 = acc[m][n][0], v1 = acc[m][n][1];
            float v2 = acc[m][n][2], v3 = acc[m][n][3];
            if (EPI != EPI_ACC) {
                float bv = bias[ng];
                v0 += bv; v1 += bv; v2 += bv; v3 += bv;
            }
            if (EPI == EPI_BF16) {
                O0[(size_t)(row0 + 0) * ldc + ng] = f2b(v0);
                O0[(size_t)(row0 + 1) * ldc + ng] = f2b(v1);
                O0[(size_t)(row0 + 2) * ldc + ng] = f2b(v2);
                O0[(size_t)(row0 + 3) * ldc + ng] = f2b(v3);
            } else if (EPI == EPI_QKV) {
                if (bn < 768) {
                    O0[(size_t)(row0 + 0) * 768 + ng] = f2b(v0 * 0.125f);
                    O0[(size_t)(row0 + 1) * 768 + ng] = f2b(v1 * 0.125f);
                    O0[(size_t)(row0 + 2) * 768 + ng] = f2b(v2 * 0.125f);
                    O0[(size_t)(row0 + 3) * 768 + ng] = f2b(v3 * 0.125f);
                } else if (bn < 1536) {
                    int c = ng - 768;
                    O1[(size_t)(row0 + 0) * 768 + c] = f2b(v0);
                    O1[(size_t)(row0 + 1) * 768 + c] = f2b(v1);
                    O1[(size_t)(row0 + 2) * 768 + c] = f2b(v2);
                    O1[(size_t)(row0 + 3) * 768 + c] = f2b(v3);
                } else {
                    int dk = ng - 1536;
                    unsigned int lo = (unsigned int)f2b(v0) | ((unsigned int)f2b(v1) << 16);
                    unsigned int hi = (unsigned int)f2b(v2) | ((unsigned int)f2b(v3) << 16);
                    uint2 o; o.x = lo; o.y = hi;
                    *(uint2*)(O2 + (size_t)dk * Mrows + row0) = o;
                }
            } else if (EPI == EPI_DUAL) {
                Cf[(size_t)(row0 + 0) * ldc + ng] = v0;
                Cf[(size_t)(row0 + 1) * ldc + ng] = v1;
                Cf[(size_t)(row0 + 2) * ldc + ng] = v2;
                Cf[(size_t)(row0 + 3) * ldc + ng] = v3;
                O0[(size_t)(row0 + 0) * ldc + ng] = f2b(v0);
                O0[(size_t)(row0 + 1) * ldc + ng] = f2b(v1);
                O0[(size_t)(row0 + 2) * ldc + ng] = f2b(v2);
                O0[(size_t)(row0 + 3) * ldc + ng] = f2b(v3);
            } else if (EPI == EPI_GELU) {
                O0[(size_t)(row0 + 0) * ldc + ng] = f2b(gelu_exact(v0));
                O0[(size_t)(row0 + 1) * ldc + ng] = f2b(gelu_exact(v1));
                O0[(size_t)(row0 + 2) * ldc + ng] = f2b(gelu_exact(v2));
                O0[(size_t)(row0 + 3) * ldc + ng] = f2b(gelu_exact(v3));
            } else if (EPI == EPI_RES) {
                Cf[(size_t)(row0 + 0) * ldc + ng] = v0 + res[(size_t)(row0 + 0) * Dt + ng];
                Cf[(size_t)(row0 + 1) * ldc + ng] = v1 + res[(size_t)(row0 + 1) * Dt + ng];
                Cf[(size_t)(row0 + 2) * ldc + ng] = v2 + res[(size_t)(row0 + 2) * Dt + ng];
                Cf[(size_t)(row0 + 3) * ldc + ng] = v3 + res[(size_t)(row0 + 3) * Dt + ng];
            } else if (EPI == EPI_ACC) {
                Cf[(size_t)(row0 + 0) * ldc + ng] += v0;
                Cf[(size_t)(row0 + 1) * ldc + ng] += v1;
                Cf[(size_t)(row0 + 2) * ldc + ng] += v2;
                Cf[(size_t)(row0 + 3) * ldc + ng] += v3;
            }
        }
    }
}

// ---------------- group attention ----------------
__global__ __launch_bounds__(256)
void group_scores_kernel(const ushort_t* __restrict__ GQK, const int* __restrict__ am,
                         float* __restrict__ smU, float* __restrict__ smD,
                         int* __restrict__ emptyF)
{
    int gi = blockIdx.x;
    int b = gi >> 9, s = gi & 511;
    int t = threadIdx.x;
    const ushort_t* qr = GQK + (size_t)gi * 1536;
    bool hasU = (s < 511) && (am[(b << 9) + s + 1] != 0);
    bool hasD = (s > 0)   && (am[(b << 9) + s - 1] != 0);
    float su = 0.0f, sd = 0.0f;
    if (hasU) {
        const ushort_t* kr = GQK + (size_t)(gi + 1) * 1536 + 768;
        for (int c = t; c < Dt; c += 256) su += b2f(qr[c]) * b2f(kr[c]);
    }
    if (hasD) {
        const ushort_t* kr = GQK + (size_t)(gi - 1) * 1536 + 768;
        for (int c = t; c < Dt; c += 256) sd += b2f(qr[c]) * b2f(kr[c]);
    }
    #pragma unroll
    for (int off = 32; off; off >>= 1) { su += __shfl_xor(su, off, 64); sd += __shfl_xor(sd, off, 64); }
    __shared__ float rU[4], rD[4];
    if ((t & 63) == 0) { rU[t >> 6] = su; rD[t >> 6] = sd; }
    __syncthreads();
    if (t == 0) {
        su = (rU[0] + rU[1] + rU[2] + rU[3]) * (1.0f / Dt);
        sd = (rD[0] + rD[1] + rD[2] + rD[3]) * (1.0f / Dt);
        float u, d2; int emp = 0;
        if (hasU && hasD) {
            float m = fmaxf(su, sd);
            float eu = __expf(su - m), ed = __expf(sd - m);
            float inv = 1.0f / (eu + ed);
            u = eu * inv; d2 = ed * inv;
        } else if (hasU) { u = 1.0f; d2 = 0.0f; }
        else if (hasD)   { u = 0.0f; d2 = 1.0f; }
        else { u = d2 = 1.0f / 512.0f; emp = 1; }
        smU[gi] = u; smD[gi] = d2; emptyF[gi] = emp;
    }
}

// per-batch prefix of log(neigh superdiag)
__global__ __launch_bounds__(64)
void prefix_kernel(const float* __restrict__ prior, const float* __restrict__ smU,
                   const float* __restrict__ smD, float* __restrict__ P)
{
    int b = blockIdx.x;
    int l = threadIdx.x;
    float lv[8];
    float run = 0.0f;
    #pragma unroll
    for (int e = 0; e < 8; ++e) {
        int j = l * 8 + e;
        float lj = 0.0f;
        if (j < 511) {
            float pr = prior[((size_t)((b << 9) + j)) * 512 + j + 1];
            float nv = pr + (1.0f - pr) *
                       sqrtf(smU[(b << 9) + j] * smD[(b << 9) + j + 1] + 1e-9f);
            lj = logf(nv + 1e-9f);
        }
        lv[e] = run;
        run += lj;
    }
    float tot = run;
    float scan = tot;
    #pragma unroll
    for (int off = 1; off < 64; off <<= 1) {
        float n = __shfl_up(scan, off, 64);
        if (l >= off) scan += n;
    }
    float excl = scan - tot;
    #pragma unroll
    for (int e = 0; e < 8; ++e)
        P[b * 512 + l * 8 + e] = excl + lv[e];
}

// fused: neigh output + C output (f32 + bf16 scratch copy)
__global__ __launch_bounds__(512)
void neigh_cfill_kernel(const float* __restrict__ prior,
                        const float* __restrict__ smU, const float* __restrict__ smD,
                        const int* __restrict__ emptyF, const float* __restrict__ P,
                        float* __restrict__ ne_out, float* __restrict__ C_out,
                        ushort_t* __restrict__ CB)
{
    int bi = blockIdx.x;
    int j  = threadIdx.x;
    int b = bi >> 9, i = bi & 511;
    int bj = (b << 9) + j;
    const float invS = 1.0f / 512.0f;
    float fij, fji;
    if (j == i + 1)      { fij = smU[bi]; fji = smD[bj]; }
    else if (j == i - 1) { fij = smD[bi]; fji = smU[bj]; }
    else { fij = emptyF[bi] ? invS : 0.0f; fji = emptyF[bj] ? invS : 0.0f; }
    float val = sqrtf(fij * fji + 1e-9f);
    float pr = prior[(size_t)bi * 512 + j];
    float nv = pr + (1.0f - pr) * val;
    ne_out[(size_t)bi * 512 + j] = nv;
    float pi = P[bi], pj = P[bj];
    float v;
    if (j > i)      v = expf(pj - pi) + 1e-9f;
    else if (j < i) v = expf(pi - pj) + 1e-9f;
    else            v = nv;
    C_out[(size_t)bi * 512 + j] = v;
    CB[(size_t)bi * 512 + j] = f2b(v);
}

// ---------------- MFMA flash MHA, static-max softmax, bf16 C, XCD swizzle ----------
#define SMAX 12.0f
__global__ __launch_bounds__(256)
void mha_mfma(const ushort_t* __restrict__ q, const ushort_t* __restrict__ k,
              const ushort_t* __restrict__ vt, const int* __restrict__ am,
              const ushort_t* __restrict__ CB, ushort_t* __restrict__ ctx)
{
    __shared__ ushort_t Qs[64][72];
    __shared__ ushort_t Ks[64][72];
    __shared__ ushort_t Vs[64][72];   // [dk][key]
    __shared__ ushort_t Ps[64][72];
    int t = threadIdx.x;
    int w = t >> 6, l = t & 63;
    int lr = l & 15, lg = l >> 4;
    int kb8 = lg << 3;
    // XCD swizzle: 1536 blocks -> chunks of 192 (2 batches) per XCD
    int bid = (blockIdx.z * 12 + blockIdx.y) * 8 + blockIdx.x;
    int sw = (bid & 7) * 192 + (bid >> 3);
    int qt = sw & 7, h = (sw >> 3) % 12, b = sw / 96;
    int hoff = h * 64;
    int q0 = qt * 64;
    int q0g = (b << 9) + q0;
    int myrow = w * 16 + lg * 4;

    #pragma unroll
    for (int i = 0; i < 2; ++i) {
        int c = t + i * 256;
        int r = c >> 3, dc = (c & 7) << 3;
        *(uint4*)&Qs[r][dc] = *(const uint4*)(q + (size_t)(q0g + r) * Dt + hoff + dc);
    }

    f32x4 oacc[4];
    #pragma unroll
    for (int n = 0; n < 4; ++n) oacc[n] = (f32x4)0.0f;
    float l_run[4] = {0.0f, 0.0f, 0.0f, 0.0f};

    for (int kb = 0; kb < 8; ++kb) {
        __syncthreads();
        #pragma unroll
        for (int i = 0; i < 2; ++i) {
            int c = t + i * 256;
            int r = c >> 3, dc = (c & 7) << 3;
            *(uint4*)&Ks[r][dc] =
                *(const uint4*)(k + (size_t)((b << 9) + kb * 64 + r) * Dt + hoff + dc);
            *(uint4*)&Vs[r][dc] =
                *(const uint4*)(vt + (size_t)(hoff + r) * Mrows + (b << 9) + kb * 64 + dc);
        }
        __syncthreads();

        int amv[4];
        #pragma unroll
        for (int n = 0; n < 4; ++n) amv[n] = am[(b << 9) + kb * 64 + n * 16 + lr];
        float cc[4][4];
        #pragma unroll
        for (int n = 0; n < 4; ++n)
            #pragma unroll
            for (int r = 0; r < 4; ++r)
                cc[n][r] = b2f(CB[(size_t)(q0g + myrow + r) * 512 + kb * 64 + n * 16 + lr]);

        f32x4 s[4];
        #pragma unroll
        for (int n = 0; n < 4; ++n) s[n] = (f32x4)0.0f;
        __builtin_amdgcn_s_setprio(1);
        #pragma unroll
        for (int ks = 0; ks < 2; ++ks) {
            bf16x8 aq = *(const bf16x8*)&Qs[w * 16 + lr][ks * 32 + kb8];
            #pragma unroll
            for (int n = 0; n < 4; ++n) {
                bf16x8 bk = *(const bf16x8*)&Ks[n * 16 + lr][ks * 32 + kb8];
                s[n] = mfma16(aq, bk, s[n]);
            }
        }
        __builtin_amdgcn_s_setprio(0);

        float pf[4][4];
        #pragma unroll
        for (int n = 0; n < 4; ++n) {
            int key = kb * 64 + n * 16 + lr;
            #pragma unroll
            for (int r = 0; r < 4; ++r) {
                int qrow = q0 + myrow + r;
                bool ok = (amv[n] != 0) || (key == qrow);
                float p = ok ? __expf(s[n][r] - SMAX) : 0.0f;
                pf[n][r] = p;
                l_run[r] += p;
            }
        }
        #pragma unroll
        for (int n = 0; n < 4; ++n)
            #pragma unroll
            for (int r = 0; r < 4; ++r)
                Ps[myrow + r][n * 16 + lr] = f2b(pf[n][r] * cc[n][r]);

        __builtin_amdgcn_s_setprio(1);
        #pragma unroll
        for (int ks = 0; ks < 2; ++ks) {
            bf16x8 ap = *(const bf16x8*)&Ps[w * 16 + lr][ks * 32 + kb8];
            #pragma unroll
            for (int n = 0; n < 4; ++n) {
                bf16x8 bv = *(const bf16x8*)&Vs[n * 16 + lr][ks * 32 + kb8];
                oacc[n] = mfma16(ap, bv, oacc[n]);
            }
        }
        __builtin_amdgcn_s_setprio(0);
    }
    #pragma unroll
    for (int r = 0; r < 4; ++r) {
        #pragma unroll
        for (int off = 1; off < 16; off <<= 1)
            l_run[r] += __shfl_xor(l_run[r], off, 64);
    }
    #pragma unroll
    for (int r = 0; r < 4; ++r) {
        float inv = 1.0f / l_run[r];
        #pragma unroll
        for (int n = 0; n < 4; ++n)
            ctx[(size_t)(q0g + myrow + r) * Dt + hoff + n * 16 + lr] =
                f2b(oacc[n][r] * inv);
    }
}

// -----------------------------------------------------------------------------------
extern "C" void kernel_launch(void* const* d_in, const int* in_sizes, int n_in,
                              void* d_out, int out_size, void* d_ws, size_t ws_size,
                              hipStream_t stream)
{
    (void)in_sizes; (void)n_in; (void)out_size; (void)ws_size;
    const float* x     = (const float*)d_in[0];
    const float* prior = (const float*)d_in[1];
    const int*   am    = (const int*)  d_in[2];
    const float* Wq = (const float*)d_in[3];   const float* bq = (const float*)d_in[4];
    const float* Wk = (const float*)d_in[5];   const float* bk = (const float*)d_in[6];
    const float* Wv = (const float*)d_in[7];   const float* bv = (const float*)d_in[8];
    const float* Wo = (const float*)d_in[9];   const float* bo = (const float*)d_in[10];
    const float* gWk = (const float*)d_in[11]; const float* gbk = (const float*)d_in[12];
    const float* gWq = (const float*)d_in[13]; const float* gbq = (const float*)d_in[14];
    const float* glng = (const float*)d_in[15]; const float* glnb = (const float*)d_in[16];
    const float* Wi = (const float*)d_in[17];  const float* bi = (const float*)d_in[18];
    const float* Wout = (const float*)d_in[19]; const float* bout = (const float*)d_in[20];
    const float* lng = (const float*)d_in[21]; const float* lnb = (const float*)d_in[22];

    float* out = (float*)d_out;
    float* o_layer = out;
    float* o_C     = out + (size_t)6291456;
    float* o_neigh = out + (size_t)10485760;
    float* o_attn  = out + (size_t)14680064;
    ushort_t* CB = (ushort_t*)o_attn;   // bf16 C scratch; Wo GEMM overwrites later

    // ---- workspace layout ----
    char* base = (char*)d_ws;
    ushort_t* WqkvT = (ushort_t*)(base);                  // [2304][768]
    ushort_t* gWqkT = (ushort_t*)(base + 3538944);        // [1536][768]
    ushort_t* WoT   = (ushort_t*)(base + 5898240);        // [768][768]
    ushort_t* WiT   = (ushort_t*)(base + 7077888);        // [3072][768]
    ushort_t* WoutT = (ushort_t*)(base + 11796480);       // [768][3072]
    float*    bqkv  = (float*)(base + 16515072);
    float*    gbqk  = (float*)(base + 16524288);
    float*    smU   = (float*)(base + 16530432);
    float*    smD   = (float*)(base + 16563200);
    float*    Ppre  = (float*)(base + 16595968);
    int*      emptyF= (int*)(base + 16628736);
    ushort_t* s0 = (ushort_t*)(base + 16661504);          // XB / CTXB
    ushort_t* s1 = (ushort_t*)(base + 29244416);          // HB / QB / AB16
    ushort_t* s2 = (ushort_t*)(base + 41827328);          // GQK / KB+VT / INTER
    ushort_t* XB = s0;    ushort_t* CTXB = s0;
    ushort_t* HB = s1;    ushort_t* QB = s1;   ushort_t* AB16 = s1;
    ushort_t* GQK = s2;   ushort_t* KB = s2;   ushort_t* INTER = s2;
    ushort_t* VT = s2 + 6291456;                          // [768][8192]

    // ---- weight prep ----
    tconv6_kernel<<<dim3(24, 24, 6), 256, 0, stream>>>(
        Wq, Wk, Wv, gWq, gWk, Wo,
        WqkvT, WqkvT + 589824, WqkvT + 1179648, gWqkT, gWqkT + 589824, WoT);
    tconv_kernel<<<dim3(96, 24), 256, 0, stream>>>(Wi, WiT, 768, 3072);
    tconv_kernel<<<dim3(24, 96), 256, 0, stream>>>(Wout, WoutT, 3072, 768);
    bconcat_kernel<<<15, 256, 0, stream>>>(bq, bk, bv, gbq, gbk, bqkv, gbqk);

    // ---- group attention ----
    lnx_kernel<<<8192, 256, 0, stream>>>(x, glng, glnb, XB, HB);
    gemm128<128, EPI_BF16><<<dim3(12, 64), 256, 0, stream>>>(
        HB, gWqkT, gbqk, nullptr, nullptr, GQK, nullptr, nullptr, 768, 768, 1536);
    group_scores_kernel<<<8192, 256, 0, stream>>>(GQK, am, smU, smD, emptyF);
    prefix_kernel<<<16, 64, 0, stream>>>(prior, smU, smD, Ppre);
    neigh_cfill_kernel<<<8192, 512, 0, stream>>>(prior, smU, smD, emptyF, Ppre,
                                                 o_neigh, o_C, CB);

    // ---- multi-head attention ----
    gemm128<128, EPI_QKV><<<dim3(18, 64), 256, 0, stream>>>(
        XB, WqkvT, bqkv, nullptr, nullptr, QB, KB, VT, 768, 768, 768);
    mha_mfma<<<dim3(8, 12, 16), 256, 0, stream>>>(QB, KB, VT, am, CB, CTXB);
    gemm128<64, EPI_DUAL><<<dim3(12, 64), 256, 0, stream>>>(
        CTXB, WoT, bo, nullptr, o_attn, AB16, nullptr, nullptr, 768, 768, 768);

    // ---- FFN, 2 chunks of 1536 over DI ----
    for (int c = 0; c < 2; ++c) {
        gemm128<128, EPI_GELU><<<dim3(12, 64), 256, 0, stream>>>(
            AB16, WiT + (size_t)c * 1536 * 768, bi + (size_t)c * 1536, nullptr,
            nullptr, INTER, nullptr, nullptr, 768, 768, 1536);
        if (c == 0)
            gemm128<64, EPI_RES><<<dim3(12, 64), 256, 0, stream>>>(
                INTER, WoutT + (size_t)c * 1536, bout, o_attn, o_layer, nullptr,
                nullptr, nullptr, 1536, 3072, 768);
        else
            gemm128<64, EPI_ACC><<<dim3(12, 64), 256, 0, stream>>>(
                INTER, WoutT + (size_t)c * 1536, nullptr, nullptr, o_layer, nullptr,
                nullptr, nullptr, 1536, 3072, 768);
    }
    ln_kernel<<<8192, 256, 0, stream>>>(o_layer, lng, lnb, o_layer);
}